// Round 5
// baseline (165.119 us; speedup 1.0000x reference)
//
#include <hip/hip_runtime.h>
#include <hip/hip_bf16.h>

// Problem constants
#define BB 128
#define TT 384
#define CC 256
#define HH 4
#define KVH 2
#define QKVW 512
#define MROWS (BB * TT)   // 49152

typedef __attribute__((ext_vector_type(8))) short short8;
typedef __attribute__((ext_vector_type(4))) float float4v;

__device__ __forceinline__ unsigned short f2b(float f) {
    union { float f; unsigned u; } v; v.f = f;
    unsigned u = v.u;
    unsigned r = (u + 0x7fffu + ((u >> 16) & 1u)) >> 16;
    return (unsigned short)r;
}
__device__ __forceinline__ float4v mfma16(short8 a, short8 b, float4v c) {
    return __builtin_amdgcn_mfma_f32_16x16x32_bf16(a, b, c, 0, 0, 0);
}
// Async global->LDS, 16B per lane. LDS dest = wave-uniform ptr + lane*16.
__device__ __forceinline__ void g2lds16(const void* g, void* l) {
    __builtin_amdgcn_global_load_lds(
        (const __attribute__((address_space(1))) unsigned int*)g,
        (__attribute__((address_space(3))) unsigned int*)l, 16, 0, 0);
}
// Pack high-halves of (a,b) with +0x8000 rounding into one dword [b_hi:a_hi].
__device__ __forceinline__ unsigned pk2bf(float a, float b) {
    union { float f; unsigned u; } x, y; x.f = a; y.f = b;
    return __builtin_amdgcn_perm(y.u + 0x8000u, x.u + 0x8000u, 0x07060302u);
}

// ---------------------------------------------------------------------------
// Prep (R5: weights + RoPE only — the 75MB x-conversion is now fused into
// gemm_qkv's A-staging, deleting the xb round-trip from the critical path).
// ---------------------------------------------------------------------------
__global__ void prep_kernel(const float* __restrict__ Wq, const float* __restrict__ Wk,
                            const float* __restrict__ Wv, const float* __restrict__ Wo,
                            unsigned short* __restrict__ WqkvT, unsigned short* __restrict__ WoT,
                            float* __restrict__ cosT, float* __restrict__ sinT) {
    int idx = blockIdx.x * 256 + threadIdx.x;
    const int N1 = QKVW * CC;          // 131072
    const int N2 = N1 + CC * CC;       // +65536
    const int N3 = N2 + TT * 32;       // +12288
    if (idx < N1) {
        int n = idx >> 8, k = idx & 255;
        float w;
        if (n < 256)      w = Wq[k * 256 + n];
        else if (n < 384) w = Wk[k * 128 + (n - 256)];
        else              w = Wv[k * 128 + (n - 384)];
        WqkvT[n * 256 + k] = f2b(w);
    } else if (idx < N2) {
        int i = idx - N1; int n = i >> 8, k = i & 255;
        WoT[n * 256 + k] = f2b(Wo[k * 256 + n]);
    } else if (idx < N3) {
        int i = idx - N2;
        int t = i >> 5, f = i & 31;
        double invf = exp2(-(double)f / 32.0 * 13.287712379549449);  // 10000^(-f/32)
        double ang = (double)t * invf;
        cosT[t * 32 + f] = (float)cos(ang);
        sinT[t * 32 + f] = (float)sin(ang);
    }
}

// ---------------------------------------------------------------------------
// GEMM1 (R5): qkv = x(fp32, converted in-staging) @ [Wq|Wk|Wv].
// A path: global fp32 -> regs -> f2b -> ds_write (T14 issue-early/write-late,
// identical LDS image & numerics as the old xb path). B path: global_load_lds.
// Double-buffered, 1 barrier/K-step (R2 skeleton, harness-verified).
// Fused RoPE + layout epilogue unchanged.
// ---------------------------------------------------------------------------
__global__ __launch_bounds__(256) void gemm_qkv_kernel(
    const float* __restrict__ X, const unsigned short* __restrict__ BT,
    unsigned short* __restrict__ Qr, unsigned short* __restrict__ Kr,
    unsigned short* __restrict__ Vt,
    const float* __restrict__ cosT, const float* __restrict__ sinT)
{
    __shared__ __align__(16) unsigned short As[2][128 * 32];
    __shared__ __align__(16) unsigned short Bs[2][128 * 32];
    const int tid  = threadIdx.x;
    const int lane = tid & 63;
    const int quad = lane >> 4, l16 = lane & 15;
    const int wave = tid >> 6;
    const int mt = ((blockIdx.x >> 5) << 3) | (blockIdx.x & 7);
    const int nt = (blockIdx.x >> 3) & 3;
    const int mbase = mt * 128, nbase = nt * 128;
    const int wmb = (wave >> 1) * 64, wnb = (wave & 1) * 64;

    float4v acc[4][4] = {};
    const int r0 = tid >> 2, kc = (tid & 3) * 8;
    const int ldsW = (tid & ~63) * 16;
    const float*          gX0 = X  + (size_t)(mbase + r0) * CC + kc;
    const unsigned short* gB0 = BT + (size_t)(nbase + r0) * CC + kc;

    float4 a0, a1, a2, a3;                       // 16 fp32 A elems in flight
    auto loadA = [&](int kt) {
        const float4* p0 = (const float4*)(gX0 + kt);
        const float4* p1 = (const float4*)(gX0 + kt + (size_t)64 * CC);
        a0 = p0[0]; a1 = p0[1]; a2 = p1[0]; a3 = p1[1];
    };
    auto writeA = [&](int bi) {
        short8 w0, w1;
        w0[0]=(short)f2b(a0.x); w0[1]=(short)f2b(a0.y); w0[2]=(short)f2b(a0.z); w0[3]=(short)f2b(a0.w);
        w0[4]=(short)f2b(a1.x); w0[5]=(short)f2b(a1.y); w0[6]=(short)f2b(a1.z); w0[7]=(short)f2b(a1.w);
        w1[0]=(short)f2b(a2.x); w1[1]=(short)f2b(a2.y); w1[2]=(short)f2b(a2.z); w1[3]=(short)f2b(a2.w);
        w1[4]=(short)f2b(a3.x); w1[5]=(short)f2b(a3.y); w1[6]=(short)f2b(a3.z); w1[7]=(short)f2b(a3.w);
        *(short8*)&As[bi][r0 * 32 + kc]        = w0;   // byte off == tid*16 (same image as g2lds)
        *(short8*)&As[bi][(r0 + 64) * 32 + kc] = w1;
    };
    auto stageB = [&](int bi, int kt) {
        g2lds16(gB0 + kt,                  (char*)&Bs[bi][0] + ldsW);
        g2lds16(gB0 + kt + (size_t)64*CC,  (char*)&Bs[bi][0] + 4096 + ldsW);
    };

    loadA(0);
    stageB(0, 0);
    writeA(0);
    for (int ks = 0; ks < 8; ks++) {
        __syncthreads();                 // buf ks&1 (A write + B g2lds) now visible
        if (ks < 7) { loadA((ks + 1) * 32); stageB((ks + 1) & 1, (ks + 1) * 32); }
        const unsigned short* Ac = &As[ks & 1][0];
        const unsigned short* Bc = &Bs[ks & 1][0];

        short8 af[4], bf_[4];
        #pragma unroll
        for (int i = 0; i < 4; i++)
            af[i] = *(const short8*)&Ac[(wmb + i * 16 + l16) * 32 + quad * 8];
        #pragma unroll
        for (int i = 0; i < 4; i++)
            bf_[i] = *(const short8*)&Bc[(wnb + i * 16 + l16) * 32 + quad * 8];
        #pragma unroll
        for (int i = 0; i < 4; i++)
            #pragma unroll
            for (int j = 0; j < 4; j++)
                acc[i][j] = mfma16(af[i], bf_[j], acc[i][j]);

        if (ks < 7) writeA((ks + 1) & 1);   // load latency hidden under MFMAs
    }

    const int gn0 = nbase + wnb;
    const int gm0 = mbase + wmb;
    if (gn0 < 384) {
        const bool isq = (gn0 < 256);
        const int  hh  = isq ? (gn0 >> 6) : ((gn0 - 256) >> 6);
        const float qs = isq ? 0.18033688011112042f : 1.0f;   // 0.125 * log2(e)
        #pragma unroll
        for (int i = 0; i < 4; i++) {
            #pragma unroll
            for (int r = 0; r < 4; r++) {
                int gm = gm0 + i * 16 + quad * 4 + r;
                int b = gm / TT, t = gm - b * TT;
                unsigned short* dst = isq
                    ? (Qr + (((size_t)b * HH  + hh) * TT + t) * 64)
                    : (Kr + (((size_t)b * KVH + hh) * TT + t) * 64);
                #pragma unroll
                for (int j = 0; j < 2; j++) {
                    int f = j * 16 + l16;
                    float cs = cosT[t * 32 + f], sn = sinT[t * 32 + f];
                    float a  = acc[i][j][r],     c2 = acc[i][j + 2][r];
                    dst[f]      = f2b((a * cs - c2 * sn) * qs);
                    dst[f + 32] = f2b((c2 * cs + a * sn) * qs);
                }
            }
        }
    } else {
        const int g = (gn0 - 384) >> 6;
        #pragma unroll
        for (int i = 0; i < 4; i++) {
            #pragma unroll
            for (int r = 0; r < 4; r++) {
                int gm = gm0 + i * 16 + quad * 4 + r;
                int b = gm / TT, s = gm - b * TT;
                int s6 = s & 63;
                int sig = (s6 & 15) * 4 + (s6 >> 4);   // key permutation
                unsigned short* dst = Vt + (((size_t)b * KVH + g) * 6 + (s >> 6)) * 4096 + sig;
                #pragma unroll
                for (int j = 0; j < 4; j++)
                    dst[(j * 16 + l16) * 64] = f2b(acc[i][j][r]);
            }
        }
    }
}

// ---------------------------------------------------------------------------
// GEMM2: out = y @ Wo, out fp32. R2 double-buffer skeleton (verified).
// ---------------------------------------------------------------------------
__global__ __launch_bounds__(256) void gemm_out_kernel(
    const unsigned short* __restrict__ A, const unsigned short* __restrict__ BT,
    float* __restrict__ C)
{
    __shared__ __align__(16) unsigned short As[2][128 * 32];
    __shared__ __align__(16) unsigned short Bs[2][128 * 32];
    const int tid  = threadIdx.x;
    const int lane = tid & 63;
    const int quad = lane >> 4, l16 = lane & 15;
    const int wave = tid >> 6;
    const int mt = ((blockIdx.x >> 4) << 3) | (blockIdx.x & 7);
    const int nt = (blockIdx.x >> 3) & 1;
    const int mbase = mt * 128, nbase = nt * 128;
    const int wmb = (wave >> 1) * 64, wnb = (wave & 1) * 64;

    float4v acc[4][4] = {};
    const int r0 = tid >> 2, kc = (tid & 3) * 8;
    const int ldsW = (tid & ~63) * 16;
    const unsigned short* gA0 = A  + (size_t)(mbase + r0) * CC + kc;
    const unsigned short* gB0 = BT + (size_t)(nbase + r0) * CC + kc;

    auto stage = [&](int bi, int kt) {
        g2lds16(gA0 + kt,                  (char*)&As[bi][0] + ldsW);
        g2lds16(gA0 + kt + (size_t)64*CC,  (char*)&As[bi][0] + 4096 + ldsW);
        g2lds16(gB0 + kt,                  (char*)&Bs[bi][0] + ldsW);
        g2lds16(gB0 + kt + (size_t)64*CC,  (char*)&Bs[bi][0] + 4096 + ldsW);
    };

    stage(0, 0);
    for (int ks = 0; ks < 8; ks++) {
        __syncthreads();                 // drains stage of ks; fences prior readers
        if (ks < 7) stage((ks + 1) & 1, (ks + 1) * 32);
        const unsigned short* Ac = &As[ks & 1][0];
        const unsigned short* Bc = &Bs[ks & 1][0];

        short8 af[4], bf_[4];
        #pragma unroll
        for (int i = 0; i < 4; i++)
            af[i] = *(const short8*)&Ac[(wmb + i * 16 + l16) * 32 + quad * 8];
        #pragma unroll
        for (int i = 0; i < 4; i++)
            bf_[i] = *(const short8*)&Bc[(wnb + i * 16 + l16) * 32 + quad * 8];
        #pragma unroll
        for (int i = 0; i < 4; i++)
            #pragma unroll
            for (int j = 0; j < 4; j++)
                acc[i][j] = mfma16(af[i], bf_[j], acc[i][j]);
    }
    #pragma unroll
    for (int i = 0; i < 4; i++)
        #pragma unroll
        for (int j = 0; j < 4; j++)
            #pragma unroll
            for (int r = 0; r < 4; r++)
                C[(size_t)(mbase + wmb + i * 16 + quad * 4 + r) * CC + nbase + wnb + j * 16 + l16]
                    = acc[i][j][r];
}

// ---------------------------------------------------------------------------
// Attention v4 (unchanged, verified): block = (b, g, p), 7 stages/block,
// K/V double-buffered, continuous stage stream, sigma-permuted P via
// ds_write_b64, fixed-max softmax, row-sums via ones-MFMA.
// ---------------------------------------------------------------------------
__global__ __launch_bounds__(256, 3) void attn_kernel(
    const unsigned short* __restrict__ Qr, const unsigned short* __restrict__ Kr,
    const unsigned short* __restrict__ Vt, unsigned short* __restrict__ y)
{
    __shared__ __align__(16) unsigned short Ks[2][64 * 64];  // 2 x 8 KB, XOR-swizzled [s][d]
    __shared__ __align__(16) unsigned short Vs[2][64 * 64];  // 2 x 8 KB, XOR-swizzled [d][sigma]
    __shared__ __align__(16) unsigned short Ps[4][32 * 64];  // per-wave [q][sigma], row-XOR

    const int tid  = threadIdx.x;
    const int lane = tid & 63;
    const int wave = tid >> 6;
    const int quad = lane >> 4, l16 = lane & 15;

    // decode with XCD co-location: all 3 p-blocks of (b,g) share bid&7
    const int xc  = blockIdx.x & 7;
    const int jj  = blockIdx.x >> 3;        // 0..95
    const int p   = jj % 3;
    const int bg  = (jj / 3) * 8 + xc;      // 0..255
    const int g   = bg & 1, b = bg >> 1;
    const int h   = g * 2 + (wave >> 1);

    const unsigned short* Kbase = Kr + ((size_t)b * KVH + g) * TT * 64;
    const unsigned short* Vbase = Vt + ((size_t)b * KVH + g) * 6 * 4096;
    const unsigned short* Qbase = Qr + ((size_t)b * HH + h) * TT * 64;
    unsigned short* ybase = y + (size_t)b * TT * CC + h * 64;
    char* Pw = (char*)&Ps[wave][0];
    const int ldsWave = (tid & ~63) * 16;
    int gc0, gc1;
    { int L0 = tid;       gc0 = ((L0 & ~7) | ((L0 & 7) ^ ((L0 >> 3) & 7))) * 8;
      int L1 = 256 + tid; gc1 = ((L1 & ~7) | ((L1 & 7) ^ ((L1 >> 3) & 7))) * 8; }

    auto stage = [&](int bi, int kt) {
        const unsigned short* kB = Kbase + (size_t)kt * 4096;
        const unsigned short* vB = Vbase + (size_t)kt * 4096;
        g2lds16(kB + gc0, (char*)&Ks[bi][0] + ldsWave);
        g2lds16(kB + gc1, (char*)&Ks[bi][0] + 4096 + ldsWave);
        g2lds16(vB + gc0, (char*)&Vs[bi][0] + ldsWave);
        g2lds16(vB + gc1, (char*)&Vs[bi][0] + 4096 + ldsWave);
    };

    short8 ones;
    #pragma unroll
    for (int j = 0; j < 8; j++) ones[j] = (short)0x3F80;   // bf16 1.0

    int seq = 0;          // global stage counter -> buffer parity
    stage(0, 0);

    for (int tph = 0; tph < 2; tph++) {
        const int qt = tph ? (5 - p) : p;
        const int qb = qt * 64 + (wave & 1) * 32;   // this wave's 32 q-rows

        // Q fragments (A-layout): m = l16, k = half*32 + quad*8
        short8 qf[2][2];
        #pragma unroll
        for (int mi = 0; mi < 2; mi++)
            #pragma unroll
            for (int half = 0; half < 2; half++)
                qf[mi][half] = *(const short8*)(Qbase
                    + (size_t)(qb + mi * 16 + l16) * 64 + half * 32 + quad * 8);

        float4v acc[2][4] = {};
        float4v accl[2]   = {};

        for (int kt = 0; kt <= qt; kt++) {
            __syncthreads();   // drains staging of current seq; fences prior readers
            // prefetch next stage in the continuous sequence (overlaps compute)
            if (kt < qt)        stage((seq + 1) & 1, kt + 1);
            else if (tph == 0)  stage((seq + 1) & 1, 0);
            const unsigned short* Kc = &Ks[seq & 1][0];
            const unsigned short* Vc = &Vs[seq & 1][0];

            // ---- S = Q . K^T (16 MFMAs) ----
            float4v s_[2][4];
            #pragma unroll
            for (int js = 0; js < 4; js++) {
                int srow = js * 16 + l16, sw = srow & 7;
                short8 kb0 = *(const short8*)((const char*)Kc + srow * 128 + ((quad ^ sw) * 16));
                short8 kb1 = *(const short8*)((const char*)Kc + srow * 128 + (((4 + quad) ^ sw) * 16));
                #pragma unroll
                for (int mi = 0; mi < 2; mi++) {
                    float4v z = {};
                    z = mfma16(qf[mi][0], kb0, z);
                    s_[mi][js] = mfma16(qf[mi][1], kb1, z);
                }
            }

            // ---- causal mask (diagonal tile only) ----
            if (kt == qt) {
                #pragma unroll
                for (int mi = 0; mi < 2; mi++)
                    #pragma unroll
                    for (int js = 0; js < 4; js++) {
                        int coll = js * 16 + l16;
                        #pragma unroll
                        for (int r = 0; r < 4; r++) {
                            int rowl = (wave & 1) * 32 + mi * 16 + quad * 4 + r;
                            if (coll > rowl) s_[mi][js][r] = -1e30f;
                        }
                    }
            }

            // ---- P = exp2(s), packed b64 store (sigma makes 4 cols contiguous) ----
            #pragma unroll
            for (int mi = 0; mi < 2; mi++)
                #pragma unroll
                for (int r = 0; r < 4; r++) {
                    float e0 = __builtin_amdgcn_exp2f(s_[mi][0][r]);
                    float e1 = __builtin_amdgcn_exp2f(s_[mi][1][r]);
                    float e2 = __builtin_amdgcn_exp2f(s_[mi][2][r]);
                    float e3 = __builtin_amdgcn_exp2f(s_[mi][3][r]);
                    unsigned long long d =
                        (unsigned long long)pk2bf(e0, e1) |
                        ((unsigned long long)pk2bf(e2, e3) << 32);
                    int rho = mi * 16 + quad * 4 + r;
                    int ch  = l16 ^ (((quad * 4 + r) & 7) << 1);
                    *(unsigned long long*)(Pw + rho * 128 + ch * 8) = d;
                }

            // ---- P A-frags (b128) + PV (16 MFMAs) + row-sums (4 MFMAs) ----
            short8 pa[2][2];
            #pragma unroll
            for (int mi = 0; mi < 2; mi++)
                #pragma unroll
                for (int half = 0; half < 2; half++) {
                    int chp = (2 * (half * 4 + quad)) ^ ((l16 & 7) << 1);
                    pa[mi][half] = *(const short8*)(Pw + (mi * 16 + l16) * 128 + chp * 8);
                }
            #pragma unroll
            for (int dj = 0; dj < 4; dj++) {
                int vrow = dj * 16 + l16, sw = vrow & 7;
                short8 vb0 = *(const short8*)((const char*)Vc + vrow * 128 + ((quad ^ sw) * 16));
                short8 vb1 = *(const short8*)((const char*)Vc + vrow * 128 + (((4 + quad) ^ sw) * 16));
                #pragma unroll
                for (int mi = 0; mi < 2; mi++) {
                    acc[mi][dj] = mfma16(pa[mi][0], vb0, acc[mi][dj]);
                    acc[mi][dj] = mfma16(pa[mi][1], vb1, acc[mi][dj]);
                }
            }
            #pragma unroll
            for (int mi = 0; mi < 2; mi++) {
                accl[mi] = mfma16(pa[mi][0], ones, accl[mi]);
                accl[mi] = mfma16(pa[mi][1], ones, accl[mi]);
            }
            seq++;
        }

        // ---- epilogue for this q-tile: y[b][t][h*64+d] = acc / l ----
        #pragma unroll
        for (int mi = 0; mi < 2; mi++) {
            float rinv[4];
            #pragma unroll
            for (int r = 0; r < 4; r++) rinv[r] = 1.0f / accl[mi][r];
            #pragma unroll
            for (int dj = 0; dj < 4; dj++)
                #pragma unroll
                for (int r = 0; r < 4; r++) {
                    int tt = qb + mi * 16 + quad * 4 + r;
                    ybase[(size_t)tt * CC + dj * 16 + l16] = f2b(acc[mi][dj][r] * rinv[r]);
                }
        }
    }
}

// ---------------------------------------------------------------------------
extern "C" void kernel_launch(void* const* d_in, const int* in_sizes, int n_in,
                              void* d_out, int out_size, void* d_ws, size_t ws_size,
                              hipStream_t stream) {
    const float* x  = (const float*)d_in[0];
    const float* Wq = (const float*)d_in[1];
    const float* Wk = (const float*)d_in[2];
    const float* Wv = (const float*)d_in[3];
    const float* Wo = (const float*)d_in[4];
    float* out = (float*)d_out;

    char* ws = (char*)d_ws;
    size_t off = 0;
    unsigned short* Qr = (unsigned short*)(ws + off); off += (size_t)BB * HH  * TT * 64 * 2;
    unsigned short* Kr = (unsigned short*)(ws + off); off += (size_t)BB * KVH * TT * 64 * 2;
    unsigned short* Vt = (unsigned short*)(ws + off); off += (size_t)BB * KVH * TT * 64 * 2;
    unsigned short* y  = (unsigned short*)(ws + off); off += (size_t)MROWS * CC * 2;
    unsigned short* WqkvT = (unsigned short*)(ws + off); off += (size_t)QKVW * CC * 2;
    unsigned short* WoT   = (unsigned short*)(ws + off); off += (size_t)CC * CC * 2;
    float* cosT = (float*)(ws + off); off += (size_t)TT * 32 * 4;
    float* sinT = (float*)(ws + off); off += (size_t)TT * 32 * 4;

    prep_kernel<<<816, 256, 0, stream>>>(Wq, Wk, Wv, Wo, WqkvT, WoT, cosT, sinT);
    gemm_qkv_kernel<<<(MROWS / 128) * 4, 256, 0, stream>>>(x, WqkvT, Qr, Kr, Vt, cosT, sinT);
    attn_kernel<<<BB * KVH * 3, 256, 0, stream>>>(Qr, Kr, Vt, y);
    gemm_out_kernel<<<(MROWS / 128) * 2, 256, 0, stream>>>(y, WoT, out);
}

// Round 6
// 164.294 us; speedup vs baseline: 1.0050x; 1.0050x over previous
//
#include <hip/hip_runtime.h>
#include <hip/hip_bf16.h>

// Problem constants
#define BB 128
#define TT 384
#define CC 256
#define HH 4
#define KVH 2
#define QKVW 512
#define MROWS (BB * TT)   // 49152

typedef __attribute__((ext_vector_type(8))) short short8;
typedef __attribute__((ext_vector_type(4))) float float4v;

__device__ __forceinline__ unsigned short f2b(float f) {
    union { float f; unsigned u; } v; v.f = f;
    unsigned u = v.u;
    unsigned r = (u + 0x7fffu + ((u >> 16) & 1u)) >> 16;
    return (unsigned short)r;
}
__device__ __forceinline__ float4v mfma16(short8 a, short8 b, float4v c) {
    return __builtin_amdgcn_mfma_f32_16x16x32_bf16(a, b, c, 0, 0, 0);
}
// Async global->LDS, 16B per lane. LDS dest = wave-uniform ptr + lane*16.
__device__ __forceinline__ void g2lds16(const void* g, void* l) {
    __builtin_amdgcn_global_load_lds(
        (const __attribute__((address_space(1))) unsigned int*)g,
        (__attribute__((address_space(3))) unsigned int*)l, 16, 0, 0);
}
// Pack high-halves of (a,b) with +0x8000 rounding into one dword [b_hi:a_hi].
__device__ __forceinline__ unsigned pk2bf(float a, float b) {
    union { float f; unsigned u; } x, y; x.f = a; y.f = b;
    return __builtin_amdgcn_perm(y.u + 0x8000u, x.u + 0x8000u, 0x07060302u);
}

// ---------------------------------------------------------------------------
// Prep: weights + RoPE only (x conversion fused into gemm_qkv).
// ---------------------------------------------------------------------------
__global__ void prep_kernel(const float* __restrict__ Wq, const float* __restrict__ Wk,
                            const float* __restrict__ Wv, const float* __restrict__ Wo,
                            unsigned short* __restrict__ WqkvT, unsigned short* __restrict__ WoT,
                            float* __restrict__ cosT, float* __restrict__ sinT) {
    int idx = blockIdx.x * 256 + threadIdx.x;
    const int N1 = QKVW * CC;          // 131072
    const int N2 = N1 + CC * CC;       // +65536
    const int N3 = N2 + TT * 32;       // +12288
    if (idx < N1) {
        int n = idx >> 8, k = idx & 255;
        float w;
        if (n < 256)      w = Wq[k * 256 + n];
        else if (n < 384) w = Wk[k * 128 + (n - 256)];
        else              w = Wv[k * 128 + (n - 384)];
        WqkvT[n * 256 + k] = f2b(w);
    } else if (idx < N2) {
        int i = idx - N1; int n = i >> 8, k = i & 255;
        WoT[n * 256 + k] = f2b(Wo[k * 256 + n]);
    } else if (idx < N3) {
        int i = idx - N2;
        int t = i >> 5, f = i & 31;
        double invf = exp2(-(double)f / 32.0 * 13.287712379549449);  // 10000^(-f/32)
        double ang = (double)t * invf;
        cosT[t * 32 + f] = (float)cos(ang);
        sinT[t * 32 + f] = (float)sin(ang);
    }
}

// ---------------------------------------------------------------------------
// GEMM1 (R6): qkv = x(fp32, converted in-staging) @ [Wq|Wk|Wv].
// R6 fixes vs R5 (measured 48.9us, MfmaUtil 9.8% -> stall-bound):
//  (1) 2-deep A register prefetch: loadA(k+2) issued at iter k, consumed by
//      writeA at end of iter k+1 -> >1 full iteration of slack vs HBM latency
//      (R5 gave it only the MFMA phase -> ~500cyc vmcnt stall every K-step).
//  (2) V epilogue via LDS transpose: was 64x scattered 2B global stores/thread
//      (every lane its own cache line); now b32 LDS writes (XOR-swizzled) ->
//      b128 LDS reads -> coalesced 16B global stores. Reuses As/Bs LDS.
// Numerics bit-identical (same f2b everywhere).
// ---------------------------------------------------------------------------
__global__ __launch_bounds__(256) void gemm_qkv_kernel(
    const float* __restrict__ X, const unsigned short* __restrict__ BT,
    unsigned short* __restrict__ Qr, unsigned short* __restrict__ Kr,
    unsigned short* __restrict__ Vt,
    const float* __restrict__ cosT, const float* __restrict__ sinT)
{
    // SH layout (halfwords): [0,4096)=A buf0, [4096,8192)=A buf1,
    // [8192,12288)=B buf0, [12288,16384)=B buf1.  Epilogue: 4 x 4096 hw
    // per-wave transpose tiles (reused after a barrier).
    __shared__ __align__(16) unsigned short SH[16384];
    const int tid  = threadIdx.x;
    const int lane = tid & 63;
    const int quad = lane >> 4, l16 = lane & 15;
    const int wave = tid >> 6;
    const int mt = ((blockIdx.x >> 5) << 3) | (blockIdx.x & 7);
    const int nt = (blockIdx.x >> 3) & 3;
    const int mbase = mt * 128, nbase = nt * 128;
    const int wmb = (wave >> 1) * 64, wnb = (wave & 1) * 64;

    float4v acc[4][4] = {};
    const int r0 = tid >> 2, kc = (tid & 3) * 8;
    const int ldsW = (tid & ~63) * 16;
    const float*          gX0 = X  + (size_t)(mbase + r0) * CC + kc;
    const unsigned short* gB0 = BT + (size_t)(nbase + r0) * CC + kc;

    float4 ar[2][4];                 // two A register sets (2-deep prefetch)
    auto loadA = [&](int st, int kt) {
        const float4* p0 = (const float4*)(gX0 + kt);
        const float4* p1 = (const float4*)(gX0 + kt + (size_t)64 * CC);
        ar[st][0] = p0[0]; ar[st][1] = p0[1]; ar[st][2] = p1[0]; ar[st][3] = p1[1];
    };
    auto writeA = [&](int bi, int st) {
        short8 w0, w1;
        w0[0]=(short)f2b(ar[st][0].x); w0[1]=(short)f2b(ar[st][0].y); w0[2]=(short)f2b(ar[st][0].z); w0[3]=(short)f2b(ar[st][0].w);
        w0[4]=(short)f2b(ar[st][1].x); w0[5]=(short)f2b(ar[st][1].y); w0[6]=(short)f2b(ar[st][1].z); w0[7]=(short)f2b(ar[st][1].w);
        w1[0]=(short)f2b(ar[st][2].x); w1[1]=(short)f2b(ar[st][2].y); w1[2]=(short)f2b(ar[st][2].z); w1[3]=(short)f2b(ar[st][2].w);
        w1[4]=(short)f2b(ar[st][3].x); w1[5]=(short)f2b(ar[st][3].y); w1[6]=(short)f2b(ar[st][3].z); w1[7]=(short)f2b(ar[st][3].w);
        *(short8*)&SH[bi * 4096 + r0 * 32 + kc]        = w0;  // byte off == tid*16
        *(short8*)&SH[bi * 4096 + (r0 + 64) * 32 + kc] = w1;
    };
    auto stageB = [&](int bi, int kt) {
        g2lds16(gB0 + kt,                  (char*)SH + 16384 + bi * 8192 + ldsW);
        g2lds16(gB0 + kt + (size_t)64*CC,  (char*)SH + 16384 + bi * 8192 + 4096 + ldsW);
    };

    loadA(0, 0);
    stageB(0, 0);
    loadA(1, 32);
    writeA(0, 0);                    // counted vmcnt wait on set0 only
    #pragma unroll
    for (int ks = 0; ks < 8; ks++) {
        __syncthreads();             // drains stageB(ks)+loadA(ks+1) from iter ks-1
        if (ks < 6) loadA(ks & 1, (ks + 2) * 32);
        if (ks < 7) stageB((ks + 1) & 1, (ks + 1) * 32);
        const unsigned short* Ac = &SH[(ks & 1) * 4096];
        const unsigned short* Bc = &SH[8192 + (ks & 1) * 4096];

        short8 af[4], bf_[4];
        #pragma unroll
        for (int i = 0; i < 4; i++)
            af[i] = *(const short8*)&Ac[(wmb + i * 16 + l16) * 32 + quad * 8];
        #pragma unroll
        for (int i = 0; i < 4; i++)
            bf_[i] = *(const short8*)&Bc[(wnb + i * 16 + l16) * 32 + quad * 8];
        #pragma unroll
        for (int i = 0; i < 4; i++)
            #pragma unroll
            for (int j = 0; j < 4; j++)
                acc[i][j] = mfma16(af[i], bf_[j], acc[i][j]);

        if (ks < 7) writeA((ks + 1) & 1, (ks + 1) & 1);  // set loaded >=1 iter ago
    }

    const int gn0 = nbase + wnb;
    const int gm0 = mbase + wmb;
    if (gn0 < 384) {
        const bool isq = (gn0 < 256);
        const int  hh  = isq ? (gn0 >> 6) : ((gn0 - 256) >> 6);
        const float qs = isq ? 0.18033688011112042f : 1.0f;   // 0.125 * log2(e)
        #pragma unroll
        for (int i = 0; i < 4; i++) {
            #pragma unroll
            for (int r = 0; r < 4; r++) {
                int gm = gm0 + i * 16 + quad * 4 + r;
                int b = gm / TT, t = gm - b * TT;
                unsigned short* dst = isq
                    ? (Qr + (((size_t)b * HH  + hh) * TT + t) * 64)
                    : (Kr + (((size_t)b * KVH + hh) * TT + t) * 64);
                #pragma unroll
                for (int j = 0; j < 2; j++) {
                    int f = j * 16 + l16;
                    float cs = cosT[t * 32 + f], sn = sinT[t * 32 + f];
                    float a  = acc[i][j][r],     c2 = acc[i][j + 2][r];
                    dst[f]      = f2b((a * cs - c2 * sn) * qs);
                    dst[f + 32] = f2b((c2 * cs + a * sn) * qs);
                }
            }
        }
    } else {
        // ---- V epilogue via per-wave LDS transpose tile (R6) ----
        // Wave owns a 64(s) x 64(d) output tile: b, g, s-tile are wave-invariant.
        const int gq = (gn0 - 384) >> 6;               // kv head
        const int bb = (mbase + wmb) / TT;
        const int tl = ((mbase + wmb) % TT) >> 6;      // s-tile 0..5
        unsigned short* Tw = &SH[wave * 4096];
        __syncthreads();                               // all waves done with As/Bs
        #pragma unroll
        for (int j = 0; j < 4; j++) {
            int dl = j * 16 + l16;                     // d 0..63
            int xr = (dl & 7) << 3;                    // XOR swizzle (bits 3-5)
            #pragma unroll
            for (int r = 0; r < 4; r++) {
                #pragma unroll
                for (int ip = 0; ip < 2; ip++) {
                    // s6 = i*16 + quad*4 + r ; sig(s6) = (s6&15)*4 + (s6>>4)
                    //    = (quad*4+r)*4 + i  -> i-pairs are adjacent sig slots.
                    unsigned v = (unsigned)f2b(acc[2 * ip][j][r])
                               | ((unsigned)f2b(acc[2 * ip + 1][j][r]) << 16);
                    int sigp = (quad * 4 + r) * 4 + 2 * ip;
                    *(unsigned*)(Tw + dl * 64 + (sigp ^ xr)) = v;
                }
            }
        }
        __syncthreads();                               // tile visible (wave-private, but cheap+safe)
        unsigned short* dstb = Vt + (((size_t)bb * KVH + gq) * 6 + tl) * 4096;
        const int c = lane & 7;
        #pragma unroll
        for (int it = 0; it < 8; it++) {
            int d = it * 8 + (lane >> 3);
            short8 v = *(const short8*)(Tw + d * 64 + (c << 3));        // addr chunk c
            *(short8*)(dstb + (size_t)d * 64 + ((c ^ (d & 7)) << 3)) = v; // logical chunk
        }
    }
}

// ---------------------------------------------------------------------------
// GEMM2: out = y @ Wo, out fp32. R2 double-buffer skeleton (verified).
// ---------------------------------------------------------------------------
__global__ __launch_bounds__(256) void gemm_out_kernel(
    const unsigned short* __restrict__ A, const unsigned short* __restrict__ BT,
    float* __restrict__ C)
{
    __shared__ __align__(16) unsigned short As[2][128 * 32];
    __shared__ __align__(16) unsigned short Bs[2][128 * 32];
    const int tid  = threadIdx.x;
    const int lane = tid & 63;
    const int quad = lane >> 4, l16 = lane & 15;
    const int wave = tid >> 6;
    const int mt = ((blockIdx.x >> 4) << 3) | (blockIdx.x & 7);
    const int nt = (blockIdx.x >> 3) & 1;
    const int mbase = mt * 128, nbase = nt * 128;
    const int wmb = (wave >> 1) * 64, wnb = (wave & 1) * 64;

    float4v acc[4][4] = {};
    const int r0 = tid >> 2, kc = (tid & 3) * 8;
    const int ldsW = (tid & ~63) * 16;
    const unsigned short* gA0 = A  + (size_t)(mbase + r0) * CC + kc;
    const unsigned short* gB0 = BT + (size_t)(nbase + r0) * CC + kc;

    auto stage = [&](int bi, int kt) {
        g2lds16(gA0 + kt,                  (char*)&As[bi][0] + ldsW);
        g2lds16(gA0 + kt + (size_t)64*CC,  (char*)&As[bi][0] + 4096 + ldsW);
        g2lds16(gB0 + kt,                  (char*)&Bs[bi][0] + ldsW);
        g2lds16(gB0 + kt + (size_t)64*CC,  (char*)&Bs[bi][0] + 4096 + ldsW);
    };

    stage(0, 0);
    for (int ks = 0; ks < 8; ks++) {
        __syncthreads();                 // drains stage of ks; fences prior readers
        if (ks < 7) stage((ks + 1) & 1, (ks + 1) * 32);
        const unsigned short* Ac = &As[ks & 1][0];
        const unsigned short* Bc = &Bs[ks & 1][0];

        short8 af[4], bf_[4];
        #pragma unroll
        for (int i = 0; i < 4; i++)
            af[i] = *(const short8*)&Ac[(wmb + i * 16 + l16) * 32 + quad * 8];
        #pragma unroll
        for (int i = 0; i < 4; i++)
            bf_[i] = *(const short8*)&Bc[(wnb + i * 16 + l16) * 32 + quad * 8];
        #pragma unroll
        for (int i = 0; i < 4; i++)
            #pragma unroll
            for (int j = 0; j < 4; j++)
                acc[i][j] = mfma16(af[i], bf_[j], acc[i][j]);
    }
    #pragma unroll
    for (int i = 0; i < 4; i++)
        #pragma unroll
        for (int j = 0; j < 4; j++)
            #pragma unroll
            for (int r = 0; r < 4; r++)
                C[(size_t)(mbase + wmb + i * 16 + quad * 4 + r) * CC + nbase + wnb + j * 16 + l16]
                    = acc[i][j][r];
}

// ---------------------------------------------------------------------------
// Attention v4 (unchanged, verified): block = (b, g, p), 7 stages/block,
// K/V double-buffered, continuous stage stream, sigma-permuted P via
// ds_write_b64, fixed-max softmax, row-sums via ones-MFMA.
// ---------------------------------------------------------------------------
__global__ __launch_bounds__(256, 3) void attn_kernel(
    const unsigned short* __restrict__ Qr, const unsigned short* __restrict__ Kr,
    const unsigned short* __restrict__ Vt, unsigned short* __restrict__ y)
{
    __shared__ __align__(16) unsigned short Ks[2][64 * 64];  // 2 x 8 KB, XOR-swizzled [s][d]
    __shared__ __align__(16) unsigned short Vs[2][64 * 64];  // 2 x 8 KB, XOR-swizzled [d][sigma]
    __shared__ __align__(16) unsigned short Ps[4][32 * 64];  // per-wave [q][sigma], row-XOR

    const int tid  = threadIdx.x;
    const int lane = tid & 63;
    const int wave = tid >> 6;
    const int quad = lane >> 4, l16 = lane & 15;

    // decode with XCD co-location: all 3 p-blocks of (b,g) share bid&7
    const int xc  = blockIdx.x & 7;
    const int jj  = blockIdx.x >> 3;        // 0..95
    const int p   = jj % 3;
    const int bg  = (jj / 3) * 8 + xc;      // 0..255
    const int g   = bg & 1, b = bg >> 1;
    const int h   = g * 2 + (wave >> 1);

    const unsigned short* Kbase = Kr + ((size_t)b * KVH + g) * TT * 64;
    const unsigned short* Vbase = Vt + ((size_t)b * KVH + g) * 6 * 4096;
    const unsigned short* Qbase = Qr + ((size_t)b * HH + h) * TT * 64;
    unsigned short* ybase = y + (size_t)b * TT * CC + h * 64;
    char* Pw = (char*)&Ps[wave][0];
    const int ldsWave = (tid & ~63) * 16;
    int gc0, gc1;
    { int L0 = tid;       gc0 = ((L0 & ~7) | ((L0 & 7) ^ ((L0 >> 3) & 7))) * 8;
      int L1 = 256 + tid; gc1 = ((L1 & ~7) | ((L1 & 7) ^ ((L1 >> 3) & 7))) * 8; }

    auto stage = [&](int bi, int kt) {
        const unsigned short* kB = Kbase + (size_t)kt * 4096;
        const unsigned short* vB = Vbase + (size_t)kt * 4096;
        g2lds16(kB + gc0, (char*)&Ks[bi][0] + ldsWave);
        g2lds16(kB + gc1, (char*)&Ks[bi][0] + 4096 + ldsWave);
        g2lds16(vB + gc0, (char*)&Vs[bi][0] + ldsWave);
        g2lds16(vB + gc1, (char*)&Vs[bi][0] + 4096 + ldsWave);
    };

    short8 ones;
    #pragma unroll
    for (int j = 0; j < 8; j++) ones[j] = (short)0x3F80;   // bf16 1.0

    int seq = 0;          // global stage counter -> buffer parity
    stage(0, 0);

    for (int tph = 0; tph < 2; tph++) {
        const int qt = tph ? (5 - p) : p;
        const int qb = qt * 64 + (wave & 1) * 32;   // this wave's 32 q-rows

        // Q fragments (A-layout): m = l16, k = half*32 + quad*8
        short8 qf[2][2];
        #pragma unroll
        for (int mi = 0; mi < 2; mi++)
            #pragma unroll
            for (int half = 0; half < 2; half++)
                qf[mi][half] = *(const short8*)(Qbase
                    + (size_t)(qb + mi * 16 + l16) * 64 + half * 32 + quad * 8);

        float4v acc[2][4] = {};
        float4v accl[2]   = {};

        for (int kt = 0; kt <= qt; kt++) {
            __syncthreads();   // drains staging of current seq; fences prior readers
            // prefetch next stage in the continuous sequence (overlaps compute)
            if (kt < qt)        stage((seq + 1) & 1, kt + 1);
            else if (tph == 0)  stage((seq + 1) & 1, 0);
            const unsigned short* Kc = &Ks[seq & 1][0];
            const unsigned short* Vc = &Vs[seq & 1][0];

            // ---- S = Q . K^T (16 MFMAs) ----
            float4v s_[2][4];
            #pragma unroll
            for (int js = 0; js < 4; js++) {
                int srow = js * 16 + l16, sw = srow & 7;
                short8 kb0 = *(const short8*)((const char*)Kc + srow * 128 + ((quad ^ sw) * 16));
                short8 kb1 = *(const short8*)((const char*)Kc + srow * 128 + (((4 + quad) ^ sw) * 16));
                #pragma unroll
                for (int mi = 0; mi < 2; mi++) {
                    float4v z = {};
                    z = mfma16(qf[mi][0], kb0, z);
                    s_[mi][js] = mfma16(qf[mi][1], kb1, z);
                }
            }

            // ---- causal mask (diagonal tile only) ----
            if (kt == qt) {
                #pragma unroll
                for (int mi = 0; mi < 2; mi++)
                    #pragma unroll
                    for (int js = 0; js < 4; js++) {
                        int coll = js * 16 + l16;
                        #pragma unroll
                        for (int r = 0; r < 4; r++) {
                            int rowl = (wave & 1) * 32 + mi * 16 + quad * 4 + r;
                            if (coll > rowl) s_[mi][js][r] = -1e30f;
                        }
                    }
            }

            // ---- P = exp2(s), packed b64 store (sigma makes 4 cols contiguous) ----
            #pragma unroll
            for (int mi = 0; mi < 2; mi++)
                #pragma unroll
                for (int r = 0; r < 4; r++) {
                    float e0 = __builtin_amdgcn_exp2f(s_[mi][0][r]);
                    float e1 = __builtin_amdgcn_exp2f(s_[mi][1][r]);
                    float e2 = __builtin_amdgcn_exp2f(s_[mi][2][r]);
                    float e3 = __builtin_amdgcn_exp2f(s_[mi][3][r]);
                    unsigned long long d =
                        (unsigned long long)pk2bf(e0, e1) |
                        ((unsigned long long)pk2bf(e2, e3) << 32);
                    int rho = mi * 16 + quad * 4 + r;
                    int ch  = l16 ^ (((quad * 4 + r) & 7) << 1);
                    *(unsigned long long*)(Pw + rho * 128 + ch * 8) = d;
                }

            // ---- P A-frags (b128) + PV (16 MFMAs) + row-sums (4 MFMAs) ----
            short8 pa[2][2];
            #pragma unroll
            for (int mi = 0; mi < 2; mi++)
                #pragma unroll
                for (int half = 0; half < 2; half++) {
                    int chp = (2 * (half * 4 + quad)) ^ ((l16 & 7) << 1);
                    pa[mi][half] = *(const short8*)(Pw + (mi * 16 + l16) * 128 + chp * 8);
                }
            #pragma unroll
            for (int dj = 0; dj < 4; dj++) {
                int vrow = dj * 16 + l16, sw = vrow & 7;
                short8 vb0 = *(const short8*)((const char*)Vc + vrow * 128 + ((quad ^ sw) * 16));
                short8 vb1 = *(const short8*)((const char*)Vc + vrow * 128 + (((4 + quad) ^ sw) * 16));
                #pragma unroll
                for (int mi = 0; mi < 2; mi++) {
                    acc[mi][dj] = mfma16(pa[mi][0], vb0, acc[mi][dj]);
                    acc[mi][dj] = mfma16(pa[mi][1], vb1, acc[mi][dj]);
                }
            }
            #pragma unroll
            for (int mi = 0; mi < 2; mi++) {
                accl[mi] = mfma16(pa[mi][0], ones, accl[mi]);
                accl[mi] = mfma16(pa[mi][1], ones, accl[mi]);
            }
            seq++;
        }

        // ---- epilogue for this q-tile: y[b][t][h*64+d] = acc / l ----
        #pragma unroll
        for (int mi = 0; mi < 2; mi++) {
            float rinv[4];
            #pragma unroll
            for (int r = 0; r < 4; r++) rinv[r] = 1.0f / accl[mi][r];
            #pragma unroll
            for (int dj = 0; dj < 4; dj++)
                #pragma unroll
                for (int r = 0; r < 4; r++) {
                    int tt = qb + mi * 16 + quad * 4 + r;
                    ybase[(size_t)tt * CC + dj * 16 + l16] = f2b(acc[mi][dj][r] * rinv[r]);
                }
        }
    }
}

// ---------------------------------------------------------------------------
extern "C" void kernel_launch(void* const* d_in, const int* in_sizes, int n_in,
                              void* d_out, int out_size, void* d_ws, size_t ws_size,
                              hipStream_t stream) {
    const float* x  = (const float*)d_in[0];
    const float* Wq = (const float*)d_in[1];
    const float* Wk = (const float*)d_in[2];
    const float* Wv = (const float*)d_in[3];
    const float* Wo = (const float*)d_in[4];
    float* out = (float*)d_out;

    char* ws = (char*)d_ws;
    size_t off = 0;
    unsigned short* Qr = (unsigned short*)(ws + off); off += (size_t)BB * HH  * TT * 64 * 2;
    unsigned short* Kr = (unsigned short*)(ws + off); off += (size_t)BB * KVH * TT * 64 * 2;
    unsigned short* Vt = (unsigned short*)(ws + off); off += (size_t)BB * KVH * TT * 64 * 2;
    unsigned short* y  = (unsigned short*)(ws + off); off += (size_t)MROWS * CC * 2;
    unsigned short* WqkvT = (unsigned short*)(ws + off); off += (size_t)QKVW * CC * 2;
    unsigned short* WoT   = (unsigned short*)(ws + off); off += (size_t)CC * CC * 2;
    float* cosT = (float*)(ws + off); off += (size_t)TT * 32 * 4;
    float* sinT = (float*)(ws + off); off += (size_t)TT * 32 * 4;

    prep_kernel<<<816, 256, 0, stream>>>(Wq, Wk, Wv, Wo, WqkvT, WoT, cosT, sinT);
    gemm_qkv_kernel<<<(MROWS / 128) * 4, 256, 0, stream>>>(x, WqkvT, Qr, Kr, Vt, cosT, sinT);
    attn_kernel<<<BB * KVH * 3, 256, 0, stream>>>(Qr, Kr, Vt, y);
    gemm_out_kernel<<<(MROWS / 128) * 2, 256, 0, stream>>>(y, WoT, out);
}

// Round 7
// 161.270 us; speedup vs baseline: 1.0239x; 1.0187x over previous
//
#include <hip/hip_runtime.h>
#include <hip/hip_bf16.h>

// Problem constants
#define BB 128
#define TT 384
#define CC 256
#define HH 4
#define KVH 2
#define QKVW 512
#define MROWS (BB * TT)   // 49152

#define CVT_BLOCKS 6144   // x fp32->bf16: 12.58M elems, 8/thread

typedef __attribute__((ext_vector_type(8))) short short8;
typedef __attribute__((ext_vector_type(4))) float float4v;

__device__ __forceinline__ unsigned short f2b(float f) {
    union { float f; unsigned u; } v; v.f = f;
    unsigned u = v.u;
    unsigned r = (u + 0x7fffu + ((u >> 16) & 1u)) >> 16;
    return (unsigned short)r;
}
__device__ __forceinline__ float4v mfma16(short8 a, short8 b, float4v c) {
    return __builtin_amdgcn_mfma_f32_16x16x32_bf16(a, b, c, 0, 0, 0);
}
// Async global->LDS, 16B per lane. LDS dest = wave-uniform ptr + lane*16.
__device__ __forceinline__ void g2lds16(const void* g, void* l) {
    __builtin_amdgcn_global_load_lds(
        (const __attribute__((address_space(1))) unsigned int*)g,
        (__attribute__((address_space(3))) unsigned int*)l, 16, 0, 0);
}
// Pack high-halves of (a,b) with +0x8000 rounding into one dword [b_hi:a_hi].
__device__ __forceinline__ unsigned pk2bf(float a, float b) {
    union { float f; unsigned u; } x, y; x.f = a; y.f = b;
    return __builtin_amdgcn_perm(y.u + 0x8000u, x.u + 0x8000u, 0x07060302u);
}

// ---------------------------------------------------------------------------
// Prep (R7: fusion reverted — x converted HERE once, not 4x inside the GEMM):
// [blocks 0..CVT_BLOCKS) convert x fp32->bf16 (8 elems/thread);
// remaining blocks pack W^T bf16 + fp64-accurate RoPE tables.
// ---------------------------------------------------------------------------
__global__ void prep_kernel(const float* __restrict__ x, unsigned short* __restrict__ xb,
                            const float* __restrict__ Wq, const float* __restrict__ Wk,
                            const float* __restrict__ Wv, const float* __restrict__ Wo,
                            unsigned short* __restrict__ WqkvT, unsigned short* __restrict__ WoT,
                            float* __restrict__ cosT, float* __restrict__ sinT) {
    if (blockIdx.x < CVT_BLOCKS) {
        size_t e = ((size_t)blockIdx.x * 256 + threadIdx.x) * 8;
        const float4* p = (const float4*)(x + e);
        float4 v0 = p[0], v1 = p[1];
        short8 w;
        w[0]=(short)f2b(v0.x); w[1]=(short)f2b(v0.y); w[2]=(short)f2b(v0.z); w[3]=(short)f2b(v0.w);
        w[4]=(short)f2b(v1.x); w[5]=(short)f2b(v1.y); w[6]=(short)f2b(v1.z); w[7]=(short)f2b(v1.w);
        *(short8*)(xb + e) = w;
        return;
    }
    int idx = (blockIdx.x - CVT_BLOCKS) * 256 + threadIdx.x;
    const int N1 = QKVW * CC;          // 131072
    const int N2 = N1 + CC * CC;       // +65536
    const int N3 = N2 + TT * 32;       // +12288
    if (idx < N1) {
        int n = idx >> 8, k = idx & 255;
        float w;
        if (n < 256)      w = Wq[k * 256 + n];
        else if (n < 384) w = Wk[k * 128 + (n - 256)];
        else              w = Wv[k * 128 + (n - 384)];
        WqkvT[n * 256 + k] = f2b(w);
    } else if (idx < N2) {
        int i = idx - N1; int n = i >> 8, k = i & 255;
        WoT[n * 256 + k] = f2b(Wo[k * 256 + n]);
    } else if (idx < N3) {
        int i = idx - N2;
        int t = i >> 5, f = i & 31;
        double invf = exp2(-(double)f / 32.0 * 13.287712379549449);  // 10000^(-f/32)
        double ang = (double)t * invf;
        cosT[t * 32 + f] = (float)cos(ang);
        sinT[t * 32 + f] = (float)sin(ang);
    }
}

// ---------------------------------------------------------------------------
// GEMM1 (R7): qkv = xb @ [Wq|Wk|Wv], dbuf g2lds staging (R2 skeleton,
// verified), fused RoPE epilogue for Q/K, and the R6-verified V epilogue:
// per-wave LDS transpose tile -> coalesced 16B stores (was 64x scattered
// 2B stores/thread, every lane its own cache line).
// SH layout (halfwords): A bufs [0,8192), B bufs [8192,16384);
// epilogue reuses all 16K hw as 4 per-wave 64x64 transpose tiles.
// ---------------------------------------------------------------------------
__global__ __launch_bounds__(256) void gemm_qkv_kernel(
    const unsigned short* __restrict__ A, const unsigned short* __restrict__ BT,
    unsigned short* __restrict__ Qr, unsigned short* __restrict__ Kr,
    unsigned short* __restrict__ Vt,
    const float* __restrict__ cosT, const float* __restrict__ sinT)
{
    __shared__ __align__(16) unsigned short SH[16384];
    const int tid  = threadIdx.x;
    const int lane = tid & 63;
    const int quad = lane >> 4, l16 = lane & 15;
    const int wave = tid >> 6;
    const int mt = ((blockIdx.x >> 5) << 3) | (blockIdx.x & 7);
    const int nt = (blockIdx.x >> 3) & 3;
    const int mbase = mt * 128, nbase = nt * 128;
    const int wmb = (wave >> 1) * 64, wnb = (wave & 1) * 64;

    float4v acc[4][4] = {};
    const int r0 = tid >> 2, kc = (tid & 3) * 8;
    const int ldsW = (tid & ~63) * 16;
    const unsigned short* gA0 = A  + (size_t)(mbase + r0) * CC + kc;
    const unsigned short* gB0 = BT + (size_t)(nbase + r0) * CC + kc;

    auto stage = [&](int bi, int kt) {
        g2lds16(gA0 + kt,                  (char*)SH + bi * 8192 + ldsW);
        g2lds16(gA0 + kt + (size_t)64*CC,  (char*)SH + bi * 8192 + 4096 + ldsW);
        g2lds16(gB0 + kt,                  (char*)SH + 16384 + bi * 8192 + ldsW);
        g2lds16(gB0 + kt + (size_t)64*CC,  (char*)SH + 16384 + bi * 8192 + 4096 + ldsW);
    };

    stage(0, 0);
    for (int ks = 0; ks < 8; ks++) {
        __syncthreads();                 // drains stage of ks; fences prior readers
        if (ks < 7) stage((ks + 1) & 1, (ks + 1) * 32);
        const unsigned short* Ac = &SH[(ks & 1) * 4096];
        const unsigned short* Bc = &SH[8192 + (ks & 1) * 4096];

        short8 af[4], bf_[4];
        #pragma unroll
        for (int i = 0; i < 4; i++)
            af[i] = *(const short8*)&Ac[(wmb + i * 16 + l16) * 32 + quad * 8];
        #pragma unroll
        for (int i = 0; i < 4; i++)
            bf_[i] = *(const short8*)&Bc[(wnb + i * 16 + l16) * 32 + quad * 8];
        #pragma unroll
        for (int i = 0; i < 4; i++)
            #pragma unroll
            for (int j = 0; j < 4; j++)
                acc[i][j] = mfma16(af[i], bf_[j], acc[i][j]);
    }

    const int gn0 = nbase + wnb;
    const int gm0 = mbase + wmb;
    if (gn0 < 384) {
        const bool isq = (gn0 < 256);
        const int  hh  = isq ? (gn0 >> 6) : ((gn0 - 256) >> 6);
        const float qs = isq ? 0.18033688011112042f : 1.0f;   // 0.125 * log2(e)
        #pragma unroll
        for (int i = 0; i < 4; i++) {
            #pragma unroll
            for (int r = 0; r < 4; r++) {
                int gm = gm0 + i * 16 + quad * 4 + r;
                int b = gm / TT, t = gm - b * TT;
                unsigned short* dst = isq
                    ? (Qr + (((size_t)b * HH  + hh) * TT + t) * 64)
                    : (Kr + (((size_t)b * KVH + hh) * TT + t) * 64);
                #pragma unroll
                for (int j = 0; j < 2; j++) {
                    int f = j * 16 + l16;
                    float cs = cosT[t * 32 + f], sn = sinT[t * 32 + f];
                    float a  = acc[i][j][r],     c2 = acc[i][j + 2][r];
                    dst[f]      = f2b((a * cs - c2 * sn) * qs);
                    dst[f + 32] = f2b((c2 * cs + a * sn) * qs);
                }
            }
        }
    } else {
        // ---- V epilogue via per-wave LDS transpose tile (verified in R6) ----
        // Wave owns a 64(s) x 64(d) output tile: b, g, s-tile are wave-invariant.
        const int gq = (gn0 - 384) >> 6;               // kv head
        const int bb = (mbase + wmb) / TT;
        const int tl = ((mbase + wmb) % TT) >> 6;      // s-tile 0..5
        unsigned short* Tw = &SH[wave * 4096];
        __syncthreads();                               // all waves done with As/Bs
        #pragma unroll
        for (int j = 0; j < 4; j++) {
            int dl = j * 16 + l16;                     // d 0..63
            int xr = (dl & 7) << 3;                    // XOR swizzle (bits 3-5)
            #pragma unroll
            for (int r = 0; r < 4; r++) {
                #pragma unroll
                for (int ip = 0; ip < 2; ip++) {
                    // s6 = i*16 + quad*4 + r ; sig(s6) = (s6&15)*4 + (s6>>4)
                    //    = (quad*4+r)*4 + i  -> i-pairs are adjacent sig slots.
                    unsigned v = (unsigned)f2b(acc[2 * ip][j][r])
                               | ((unsigned)f2b(acc[2 * ip + 1][j][r]) << 16);
                    int sigp = (quad * 4 + r) * 4 + 2 * ip;
                    *(unsigned*)(Tw + dl * 64 + (sigp ^ xr)) = v;
                }
            }
        }
        __syncthreads();                               // tile visible
        unsigned short* dstb = Vt + (((size_t)bb * KVH + gq) * 6 + tl) * 4096;
        const int c = lane & 7;
        #pragma unroll
        for (int it = 0; it < 8; it++) {
            int d = it * 8 + (lane >> 3);
            short8 v = *(const short8*)(Tw + d * 64 + (c << 3));        // addr chunk c
            *(short8*)(dstb + (size_t)d * 64 + ((c ^ (d & 7)) << 3)) = v; // logical chunk
        }
    }
}

// ---------------------------------------------------------------------------
// GEMM2: out = y @ Wo, out fp32. R2 double-buffer skeleton (verified).
// ---------------------------------------------------------------------------
__global__ __launch_bounds__(256) void gemm_out_kernel(
    const unsigned short* __restrict__ A, const unsigned short* __restrict__ BT,
    float* __restrict__ C)
{
    __shared__ __align__(16) unsigned short As[2][128 * 32];
    __shared__ __align__(16) unsigned short Bs[2][128 * 32];
    const int tid  = threadIdx.x;
    const int lane = tid & 63;
    const int quad = lane >> 4, l16 = lane & 15;
    const int wave = tid >> 6;
    const int mt = ((blockIdx.x >> 4) << 3) | (blockIdx.x & 7);
    const int nt = (blockIdx.x >> 3) & 1;
    const int mbase = mt * 128, nbase = nt * 128;
    const int wmb = (wave >> 1) * 64, wnb = (wave & 1) * 64;

    float4v acc[4][4] = {};
    const int r0 = tid >> 2, kc = (tid & 3) * 8;
    const int ldsW = (tid & ~63) * 16;
    const unsigned short* gA0 = A  + (size_t)(mbase + r0) * CC + kc;
    const unsigned short* gB0 = BT + (size_t)(nbase + r0) * CC + kc;

    auto stage = [&](int bi, int kt) {
        g2lds16(gA0 + kt,                  (char*)&As[bi][0] + ldsW);
        g2lds16(gA0 + kt + (size_t)64*CC,  (char*)&As[bi][0] + 4096 + ldsW);
        g2lds16(gB0 + kt,                  (char*)&Bs[bi][0] + ldsW);
        g2lds16(gB0 + kt + (size_t)64*CC,  (char*)&Bs[bi][0] + 4096 + ldsW);
    };

    stage(0, 0);
    for (int ks = 0; ks < 8; ks++) {
        __syncthreads();                 // drains stage of ks; fences prior readers
        if (ks < 7) stage((ks + 1) & 1, (ks + 1) * 32);
        const unsigned short* Ac = &As[ks & 1][0];
        const unsigned short* Bc = &Bs[ks & 1][0];

        short8 af[4], bf_[4];
        #pragma unroll
        for (int i = 0; i < 4; i++)
            af[i] = *(const short8*)&Ac[(wmb + i * 16 + l16) * 32 + quad * 8];
        #pragma unroll
        for (int i = 0; i < 4; i++)
            bf_[i] = *(const short8*)&Bc[(wnb + i * 16 + l16) * 32 + quad * 8];
        #pragma unroll
        for (int i = 0; i < 4; i++)
            #pragma unroll
            for (int j = 0; j < 4; j++)
                acc[i][j] = mfma16(af[i], bf_[j], acc[i][j]);
    }
    #pragma unroll
    for (int i = 0; i < 4; i++)
        #pragma unroll
        for (int j = 0; j < 4; j++)
            #pragma unroll
            for (int r = 0; r < 4; r++)
                C[(size_t)(mbase + wmb + i * 16 + quad * 4 + r) * CC + nbase + wnb + j * 16 + l16]
                    = acc[i][j][r];
}

// ---------------------------------------------------------------------------
// Attention v4 (unchanged, verified): block = (b, g, p), 7 stages/block,
// K/V double-buffered, continuous stage stream, sigma-permuted P via
// ds_write_b64, fixed-max softmax, row-sums via ones-MFMA.
// ---------------------------------------------------------------------------
__global__ __launch_bounds__(256, 3) void attn_kernel(
    const unsigned short* __restrict__ Qr, const unsigned short* __restrict__ Kr,
    const unsigned short* __restrict__ Vt, unsigned short* __restrict__ y)
{
    __shared__ __align__(16) unsigned short Ks[2][64 * 64];  // 2 x 8 KB, XOR-swizzled [s][d]
    __shared__ __align__(16) unsigned short Vs[2][64 * 64];  // 2 x 8 KB, XOR-swizzled [d][sigma]
    __shared__ __align__(16) unsigned short Ps[4][32 * 64];  // per-wave [q][sigma], row-XOR

    const int tid  = threadIdx.x;
    const int lane = tid & 63;
    const int wave = tid >> 6;
    const int quad = lane >> 4, l16 = lane & 15;

    // decode with XCD co-location: all 3 p-blocks of (b,g) share bid&7
    const int xc  = blockIdx.x & 7;
    const int jj  = blockIdx.x >> 3;        // 0..95
    const int p   = jj % 3;
    const int bg  = (jj / 3) * 8 + xc;      // 0..255
    const int g   = bg & 1, b = bg >> 1;
    const int h   = g * 2 + (wave >> 1);

    const unsigned short* Kbase = Kr + ((size_t)b * KVH + g) * TT * 64;
    const unsigned short* Vbase = Vt + ((size_t)b * KVH + g) * 6 * 4096;
    const unsigned short* Qbase = Qr + ((size_t)b * HH + h) * TT * 64;
    unsigned short* ybase = y + (size_t)b * TT * CC + h * 64;
    char* Pw = (char*)&Ps[wave][0];
    const int ldsWave = (tid & ~63) * 16;
    int gc0, gc1;
    { int L0 = tid;       gc0 = ((L0 & ~7) | ((L0 & 7) ^ ((L0 >> 3) & 7))) * 8;
      int L1 = 256 + tid; gc1 = ((L1 & ~7) | ((L1 & 7) ^ ((L1 >> 3) & 7))) * 8; }

    auto stage = [&](int bi, int kt) {
        const unsigned short* kB = Kbase + (size_t)kt * 4096;
        const unsigned short* vB = Vbase + (size_t)kt * 4096;
        g2lds16(kB + gc0, (char*)&Ks[bi][0] + ldsWave);
        g2lds16(kB + gc1, (char*)&Ks[bi][0] + 4096 + ldsWave);
        g2lds16(vB + gc0, (char*)&Vs[bi][0] + ldsWave);
        g2lds16(vB + gc1, (char*)&Vs[bi][0] + 4096 + ldsWave);
    };

    short8 ones;
    #pragma unroll
    for (int j = 0; j < 8; j++) ones[j] = (short)0x3F80;   // bf16 1.0

    int seq = 0;          // global stage counter -> buffer parity
    stage(0, 0);

    for (int tph = 0; tph < 2; tph++) {
        const int qt = tph ? (5 - p) : p;
        const int qb = qt * 64 + (wave & 1) * 32;   // this wave's 32 q-rows

        // Q fragments (A-layout): m = l16, k = half*32 + quad*8
        short8 qf[2][2];
        #pragma unroll
        for (int mi = 0; mi < 2; mi++)
            #pragma unroll
            for (int half = 0; half < 2; half++)
                qf[mi][half] = *(const short8*)(Qbase
                    + (size_t)(qb + mi * 16 + l16) * 64 + half * 32 + quad * 8);

        float4v acc[2][4] = {};
        float4v accl[2]   = {};

        for (int kt = 0; kt <= qt; kt++) {
            __syncthreads();   // drains staging of current seq; fences prior readers
            // prefetch next stage in the continuous sequence (overlaps compute)
            if (kt < qt)        stage((seq + 1) & 1, kt + 1);
            else if (tph == 0)  stage((seq + 1) & 1, 0);
            const unsigned short* Kc = &Ks[seq & 1][0];
            const unsigned short* Vc = &Vs[seq & 1][0];

            // ---- S = Q . K^T (16 MFMAs) ----
            float4v s_[2][4];
            #pragma unroll
            for (int js = 0; js < 4; js++) {
                int srow = js * 16 + l16, sw = srow & 7;
                short8 kb0 = *(const short8*)((const char*)Kc + srow * 128 + ((quad ^ sw) * 16));
                short8 kb1 = *(const short8*)((const char*)Kc + srow * 128 + (((4 + quad) ^ sw) * 16));
                #pragma unroll
                for (int mi = 0; mi < 2; mi++) {
                    float4v z = {};
                    z = mfma16(qf[mi][0], kb0, z);
                    s_[mi][js] = mfma16(qf[mi][1], kb1, z);
                }
            }

            // ---- causal mask (diagonal tile only) ----
            if (kt == qt) {
                #pragma unroll
                for (int mi = 0; mi < 2; mi++)
                    #pragma unroll
                    for (int js = 0; js < 4; js++) {
                        int coll = js * 16 + l16;
                        #pragma unroll
                        for (int r = 0; r < 4; r++) {
                            int rowl = (wave & 1) * 32 + mi * 16 + quad * 4 + r;
                            if (coll > rowl) s_[mi][js][r] = -1e30f;
                        }
                    }
            }

            // ---- P = exp2(s), packed b64 store (sigma makes 4 cols contiguous) ----
            #pragma unroll
            for (int mi = 0; mi < 2; mi++)
                #pragma unroll
                for (int r = 0; r < 4; r++) {
                    float e0 = __builtin_amdgcn_exp2f(s_[mi][0][r]);
                    float e1 = __builtin_amdgcn_exp2f(s_[mi][1][r]);
                    float e2 = __builtin_amdgcn_exp2f(s_[mi][2][r]);
                    float e3 = __builtin_amdgcn_exp2f(s_[mi][3][r]);
                    unsigned long long d =
                        (unsigned long long)pk2bf(e0, e1) |
                        ((unsigned long long)pk2bf(e2, e3) << 32);
                    int rho = mi * 16 + quad * 4 + r;
                    int ch  = l16 ^ (((quad * 4 + r) & 7) << 1);
                    *(unsigned long long*)(Pw + rho * 128 + ch * 8) = d;
                }

            // ---- P A-frags (b128) + PV (16 MFMAs) + row-sums (4 MFMAs) ----
            short8 pa[2][2];
            #pragma unroll
            for (int mi = 0; mi < 2; mi++)
                #pragma unroll
                for (int half = 0; half < 2; half++) {
                    int chp = (2 * (half * 4 + quad)) ^ ((l16 & 7) << 1);
                    pa[mi][half] = *(const short8*)(Pw + (mi * 16 + l16) * 128 + chp * 8);
                }
            #pragma unroll
            for (int dj = 0; dj < 4; dj++) {
                int vrow = dj * 16 + l16, sw = vrow & 7;
                short8 vb0 = *(const short8*)((const char*)Vc + vrow * 128 + ((quad ^ sw) * 16));
                short8 vb1 = *(const short8*)((const char*)Vc + vrow * 128 + (((4 + quad) ^ sw) * 16));
                #pragma unroll
                for (int mi = 0; mi < 2; mi++) {
                    acc[mi][dj] = mfma16(pa[mi][0], vb0, acc[mi][dj]);
                    acc[mi][dj] = mfma16(pa[mi][1], vb1, acc[mi][dj]);
                }
            }
            #pragma unroll
            for (int mi = 0; mi < 2; mi++) {
                accl[mi] = mfma16(pa[mi][0], ones, accl[mi]);
                accl[mi] = mfma16(pa[mi][1], ones, accl[mi]);
            }
            seq++;
        }

        // ---- epilogue for this q-tile: y[b][t][h*64+d] = acc / l ----
        #pragma unroll
        for (int mi = 0; mi < 2; mi++) {
            float rinv[4];
            #pragma unroll
            for (int r = 0; r < 4; r++) rinv[r] = 1.0f / accl[mi][r];
            #pragma unroll
            for (int dj = 0; dj < 4; dj++)
                #pragma unroll
                for (int r = 0; r < 4; r++) {
                    int tt = qb + mi * 16 + quad * 4 + r;
                    ybase[(size_t)tt * CC + dj * 16 + l16] = f2b(acc[mi][dj][r] * rinv[r]);
                }
        }
    }
}

// ---------------------------------------------------------------------------
extern "C" void kernel_launch(void* const* d_in, const int* in_sizes, int n_in,
                              void* d_out, int out_size, void* d_ws, size_t ws_size,
                              hipStream_t stream) {
    const float* x  = (const float*)d_in[0];
    const float* Wq = (const float*)d_in[1];
    const float* Wk = (const float*)d_in[2];
    const float* Wv = (const float*)d_in[3];
    const float* Wo = (const float*)d_in[4];
    float* out = (float*)d_out;

    char* ws = (char*)d_ws;
    size_t off = 0;
    unsigned short* xb = (unsigned short*)(ws + off); off += (size_t)MROWS * CC * 2;
    unsigned short* Qr = (unsigned short*)(ws + off); off += (size_t)BB * HH  * TT * 64 * 2;
    unsigned short* Kr = (unsigned short*)(ws + off); off += (size_t)BB * KVH * TT * 64 * 2;
    unsigned short* Vt = (unsigned short*)(ws + off); off += (size_t)BB * KVH * TT * 64 * 2;
    unsigned short* y  = (unsigned short*)(ws + off); off += (size_t)MROWS * CC * 2;
    unsigned short* WqkvT = (unsigned short*)(ws + off); off += (size_t)QKVW * CC * 2;
    unsigned short* WoT   = (unsigned short*)(ws + off); off += (size_t)CC * CC * 2;
    float* cosT = (float*)(ws + off); off += (size_t)TT * 32 * 4;
    float* sinT = (float*)(ws + off); off += (size_t)TT * 32 * 4;

    prep_kernel<<<CVT_BLOCKS + 816, 256, 0, stream>>>(x, xb, Wq, Wk, Wv, Wo,
                                                      WqkvT, WoT, cosT, sinT);
    gemm_qkv_kernel<<<(MROWS / 128) * 4, 256, 0, stream>>>(xb, WqkvT, Qr, Kr, Vt, cosT, sinT);
    attn_kernel<<<BB * KVH * 3, 256, 0, stream>>>(Qr, Kr, Vt, y);
    gemm_out_kernel<<<(MROWS / 128) * 2, 256, 0, stream>>>(y, WoT, out);
}

// Round 10
// 159.788 us; speedup vs baseline: 1.0334x; 1.0093x over previous
//
#include <hip/hip_runtime.h>
#include <hip/hip_bf16.h>

// Problem constants
#define BB 128
#define TT 384
#define CC 256
#define HH 4
#define KVH 2
#define QKVW 512
#define MROWS (BB * TT)   // 49152

#define CVT_BLOCKS 6144   // x fp32->bf16: 12.58M elems, 8/thread

typedef __attribute__((ext_vector_type(8))) short short8;
typedef __attribute__((ext_vector_type(4))) float float4v;

__device__ __forceinline__ unsigned short f2b(float f) {
    union { float f; unsigned u; } v; v.f = f;
    unsigned u = v.u;
    unsigned r = (u + 0x7fffu + ((u >> 16) & 1u)) >> 16;
    return (unsigned short)r;
}
__device__ __forceinline__ float4v mfma16(short8 a, short8 b, float4v c) {
    return __builtin_amdgcn_mfma_f32_16x16x32_bf16(a, b, c, 0, 0, 0);
}
// Async global->LDS, 16B per lane. LDS dest = wave-uniform ptr + lane*16.
__device__ __forceinline__ void g2lds16(const void* g, void* l) {
    __builtin_amdgcn_global_load_lds(
        (const __attribute__((address_space(1))) unsigned int*)g,
        (__attribute__((address_space(3))) unsigned int*)l, 16, 0, 0);
}
// Pack high-halves of (a,b) with +0x8000 rounding into one dword [b_hi:a_hi].
__device__ __forceinline__ unsigned pk2bf(float a, float b) {
    union { float f; unsigned u; } x, y; x.f = a; y.f = b;
    return __builtin_amdgcn_perm(y.u + 0x8000u, x.u + 0x8000u, 0x07060302u);
}

// ---------------------------------------------------------------------------
// Prep (fused): [blocks 0..CVT_BLOCKS) convert x fp32->bf16 (8 elems/thread);
// remaining blocks pack W^T bf16 + fp64-accurate RoPE tables.
// ---------------------------------------------------------------------------
__global__ void prep_kernel(const float* __restrict__ x, unsigned short* __restrict__ xb,
                            const float* __restrict__ Wq, const float* __restrict__ Wk,
                            const float* __restrict__ Wv, const float* __restrict__ Wo,
                            unsigned short* __restrict__ WqkvT, unsigned short* __restrict__ WoT,
                            float* __restrict__ cosT, float* __restrict__ sinT) {
    if (blockIdx.x < CVT_BLOCKS) {
        size_t e = ((size_t)blockIdx.x * 256 + threadIdx.x) * 8;
        const float4* p = (const float4*)(x + e);
        float4 v0 = p[0], v1 = p[1];
        short8 w;
        w[0]=(short)f2b(v0.x); w[1]=(short)f2b(v0.y); w[2]=(short)f2b(v0.z); w[3]=(short)f2b(v0.w);
        w[4]=(short)f2b(v1.x); w[5]=(short)f2b(v1.y); w[6]=(short)f2b(v1.z); w[7]=(short)f2b(v1.w);
        *(short8*)(xb + e) = w;
        return;
    }
    int idx = (blockIdx.x - CVT_BLOCKS) * 256 + threadIdx.x;
    const int N1 = QKVW * CC;          // 131072
    const int N2 = N1 + CC * CC;       // +65536
    const int N3 = N2 + TT * 32;       // +12288
    if (idx < N1) {
        int n = idx >> 8, k = idx & 255;
        float w;
        if (n < 256)      w = Wq[k * 256 + n];
        else if (n < 384) w = Wk[k * 128 + (n - 256)];
        else              w = Wv[k * 128 + (n - 384)];
        WqkvT[n * 256 + k] = f2b(w);
    } else if (idx < N2) {
        int i = idx - N1; int n = i >> 8, k = i & 255;
        WoT[n * 256 + k] = f2b(Wo[k * 256 + n]);
    } else if (idx < N3) {
        int i = idx - N2;
        int t = i >> 5, f = i & 31;
        double invf = exp2(-(double)f / 32.0 * 13.287712379549449);  // 10000^(-f/32)
        double ang = (double)t * invf;
        cosT[t * 32 + f] = (float)cos(ang);
        sinT[t * 32 + f] = (float)sin(ang);
    }
}

// ---------------------------------------------------------------------------
// GEMM1 (m97-style): qkv = xb @ [Wq|Wk|Wv], async LDS staging, fused RoPE +
// layout epilogue. XCD swizzle: the 4 nt-variants of one mt share an XCD.
// Emits: Qr [b][h][t][64] (*0.125*log2e), Kr [b][g][s][64],
//        Vt [b][g][s/64][d][sigma(s%64)]  (sigma = attn's P-column permute).
// ---------------------------------------------------------------------------
__global__ __launch_bounds__(256) void gemm_qkv_kernel(
    const unsigned short* __restrict__ A, const unsigned short* __restrict__ BT,
    unsigned short* __restrict__ Qr, unsigned short* __restrict__ Kr,
    unsigned short* __restrict__ Vt,
    const float* __restrict__ cosT, const float* __restrict__ sinT)
{
    __shared__ __align__(16) unsigned short As[128 * 32];
    __shared__ __align__(16) unsigned short Bs[128 * 32];
    const int tid  = threadIdx.x;
    const int lane = tid & 63;
    const int quad = lane >> 4, l16 = lane & 15;
    const int wave = tid >> 6;
    const int mt = ((blockIdx.x >> 5) << 3) | (blockIdx.x & 7);
    const int nt = (blockIdx.x >> 3) & 3;
    const int mbase = mt * 128, nbase = nt * 128;
    const int wmb = (wave >> 1) * 64, wnb = (wave & 1) * 64;

    float4v acc[4][4] = {};
    const int r0 = tid >> 2, kc = (tid & 3) * 8;
    const int ldsW = (tid & ~63) * 16;
    const unsigned short* gA0 = A  + (size_t)(mbase + r0) * CC + kc;
    const unsigned short* gB0 = BT + (size_t)(nbase + r0) * CC + kc;

    for (int kt = 0; kt < CC; kt += 32) {
        __syncthreads();
        g2lds16(gA0 + kt,                  (char*)As + ldsW);
        g2lds16(gA0 + kt + (size_t)64*CC,  (char*)As + 4096 + ldsW);
        g2lds16(gB0 + kt,                  (char*)Bs + ldsW);
        g2lds16(gB0 + kt + (size_t)64*CC,  (char*)Bs + 4096 + ldsW);
        __syncthreads();

        short8 af[4], bf_[4];
        #pragma unroll
        for (int i = 0; i < 4; i++)
            af[i] = *(const short8*)&As[(wmb + i * 16 + l16) * 32 + quad * 8];
        #pragma unroll
        for (int i = 0; i < 4; i++)
            bf_[i] = *(const short8*)&Bs[(wnb + i * 16 + l16) * 32 + quad * 8];
        #pragma unroll
        for (int i = 0; i < 4; i++)
            #pragma unroll
            for (int j = 0; j < 4; j++)
                acc[i][j] = mfma16(af[i], bf_[j], acc[i][j]);
    }

    const int gn0 = nbase + wnb;
    const int gm0 = mbase + wmb;
    if (gn0 < 384) {
        const bool isq = (gn0 < 256);
        const int  hh  = isq ? (gn0 >> 6) : ((gn0 - 256) >> 6);
        const float qs = isq ? 0.18033688011112042f : 1.0f;   // 0.125 * log2(e)
        #pragma unroll
        for (int i = 0; i < 4; i++) {
            #pragma unroll
            for (int r = 0; r < 4; r++) {
                int gm = gm0 + i * 16 + quad * 4 + r;
                int b = gm / TT, t = gm - b * TT;
                unsigned short* dst = isq
                    ? (Qr + (((size_t)b * HH  + hh) * TT + t) * 64)
                    : (Kr + (((size_t)b * KVH + hh) * TT + t) * 64);
                #pragma unroll
                for (int j = 0; j < 2; j++) {
                    int f = j * 16 + l16;
                    float cs = cosT[t * 32 + f], sn = sinT[t * 32 + f];
                    float a  = acc[i][j][r],     c2 = acc[i][j + 2][r];
                    dst[f]      = f2b((a * cs - c2 * sn) * qs);
                    dst[f + 32] = f2b((c2 * cs + a * sn) * qs);
                }
            }
        }
    } else {
        const int g = (gn0 - 384) >> 6;
        #pragma unroll
        for (int i = 0; i < 4; i++) {
            #pragma unroll
            for (int r = 0; r < 4; r++) {
                int gm = gm0 + i * 16 + quad * 4 + r;
                int b = gm / TT, s = gm - b * TT;
                int s6 = s & 63;
                int sig = (s6 & 15) * 4 + (s6 >> 4);   // key permutation
                unsigned short* dst = Vt + (((size_t)b * KVH + g) * 6 + (s >> 6)) * 4096 + sig;
                #pragma unroll
                for (int j = 0; j < 4; j++)
                    dst[(j * 16 + l16) * 64] = f2b(acc[i][j][r]);
            }
        }
    }
}

// ---------------------------------------------------------------------------
// GEMM2 (m97-style): out = y @ Wo, out fp32. XCD swizzle on (mt,nt).
// ---------------------------------------------------------------------------
__global__ __launch_bounds__(256) void gemm_out_kernel(
    const unsigned short* __restrict__ A, const unsigned short* __restrict__ BT,
    float* __restrict__ C)
{
    __shared__ __align__(16) unsigned short As[128 * 32];
    __shared__ __align__(16) unsigned short Bs[128 * 32];
    const int tid  = threadIdx.x;
    const int lane = tid & 63;
    const int quad = lane >> 4, l16 = lane & 15;
    const int wave = tid >> 6;
    const int mt = ((blockIdx.x >> 4) << 3) | (blockIdx.x & 7);
    const int nt = (blockIdx.x >> 3) & 1;
    const int mbase = mt * 128, nbase = nt * 128;
    const int wmb = (wave >> 1) * 64, wnb = (wave & 1) * 64;

    float4v acc[4][4] = {};
    const int r0 = tid >> 2, kc = (tid & 3) * 8;
    const int ldsW = (tid & ~63) * 16;
    const unsigned short* gA0 = A  + (size_t)(mbase + r0) * CC + kc;
    const unsigned short* gB0 = BT + (size_t)(nbase + r0) * CC + kc;

    for (int kt = 0; kt < CC; kt += 32) {
        __syncthreads();
        g2lds16(gA0 + kt,                  (char*)As + ldsW);
        g2lds16(gA0 + kt + (size_t)64*CC,  (char*)As + 4096 + ldsW);
        g2lds16(gB0 + kt,                  (char*)Bs + ldsW);
        g2lds16(gB0 + kt + (size_t)64*CC,  (char*)Bs + 4096 + ldsW);
        __syncthreads();

        short8 af[4], bf_[4];
        #pragma unroll
        for (int i = 0; i < 4; i++)
            af[i] = *(const short8*)&As[(wmb + i * 16 + l16) * 32 + quad * 8];
        #pragma unroll
        for (int i = 0; i < 4; i++)
            bf_[i] = *(const short8*)&Bs[(wnb + i * 16 + l16) * 32 + quad * 8];
        #pragma unroll
        for (int i = 0; i < 4; i++)
            #pragma unroll
            for (int j = 0; j < 4; j++)
                acc[i][j] = mfma16(af[i], bf_[j], acc[i][j]);
    }
    #pragma unroll
    for (int i = 0; i < 4; i++)
        #pragma unroll
        for (int j = 0; j < 4; j++)
            #pragma unroll
            for (int r = 0; r < 4; r++)
                C[(size_t)(mbase + wmb + i * 16 + quad * 4 + r) * CC + nbase + wnb + j * 16 + l16]
                    = acc[i][j][r];
}

// ---------------------------------------------------------------------------
// Attention v4: block = (b, g, p) computes q-tile p fully (kt=0..p), writes
// it, then q-tile 5-p (kt=0..5-p): (p+1)+(6-p)=7 stages for EVERY block
// (perfect balance), with only ONE acc/accl/qf set live (no spill).
// K/V double-buffered, stage stream continuous across the tile switch.
// P stored via key-permutation sigma (lane's 4 score cols contiguous ->
// ds_write_b64). Fixed-max softmax; row-sums via ones-MFMA. No shuffles.
// ---------------------------------------------------------------------------
__global__ __launch_bounds__(256, 3) void attn_kernel(
    const unsigned short* __restrict__ Qr, const unsigned short* __restrict__ Kr,
    const unsigned short* __restrict__ Vt, unsigned short* __restrict__ y)
{
    __shared__ __align__(16) unsigned short Ks[2][64 * 64];  // 2 x 8 KB, XOR-swizzled [s][d]
    __shared__ __align__(16) unsigned short Vs[2][64 * 64];  // 2 x 8 KB, XOR-swizzled [d][sigma]
    __shared__ __align__(16) unsigned short Ps[4][32 * 64];  // per-wave [q][sigma], row-XOR

    const int tid  = threadIdx.x;
    const int lane = tid & 63;
    const int wave = tid >> 6;
    const int quad = lane >> 4, l16 = lane & 15;

    // decode with XCD co-location: all 3 p-blocks of (b,g) share bid&7
    const int xc  = blockIdx.x & 7;
    const int jj  = blockIdx.x >> 3;        // 0..95
    const int p   = jj % 3;
    const int bg  = (jj / 3) * 8 + xc;      // 0..255
    const int g   = bg & 1, b = bg >> 1;
    const int h   = g * 2 + (wave >> 1);

    const unsigned short* Kbase = Kr + ((size_t)b * KVH + g) * TT * 64;
    const unsigned short* Vbase = Vt + ((size_t)b * KVH + g) * 6 * 4096;
    const unsigned short* Qbase = Qr + ((size_t)b * HH + h) * TT * 64;
    unsigned short* ybase = y + (size_t)b * TT * CC + h * 64;
    char* Pw = (char*)&Ps[wave][0];
    const int ldsWave = (tid & ~63) * 16;
    int gc0, gc1;
    { int L0 = tid;       gc0 = ((L0 & ~7) | ((L0 & 7) ^ ((L0 >> 3) & 7))) * 8;
      int L1 = 256 + tid; gc1 = ((L1 & ~7) | ((L1 & 7) ^ ((L1 >> 3) & 7))) * 8; }

    auto stage = [&](int bi, int kt) {
        const unsigned short* kB = Kbase + (size_t)kt * 4096;
        const unsigned short* vB = Vbase + (size_t)kt * 4096;
        g2lds16(kB + gc0, (char*)&Ks[bi][0] + ldsWave);
        g2lds16(kB + gc1, (char*)&Ks[bi][0] + 4096 + ldsWave);
        g2lds16(vB + gc0, (char*)&Vs[bi][0] + ldsWave);
        g2lds16(vB + gc1, (char*)&Vs[bi][0] + 4096 + ldsWave);
    };

    short8 ones;
    #pragma unroll
    for (int j = 0; j < 8; j++) ones[j] = (short)0x3F80;   // bf16 1.0

    int seq = 0;          // global stage counter -> buffer parity
    stage(0, 0);

    for (int tph = 0; tph < 2; tph++) {
        const int qt = tph ? (5 - p) : p;
        const int qb = qt * 64 + (wave & 1) * 32;   // this wave's 32 q-rows

        // Q fragments (A-layout): m = l16, k = half*32 + quad*8
        short8 qf[2][2];
        #pragma unroll
        for (int mi = 0; mi < 2; mi++)
            #pragma unroll
            for (int half = 0; half < 2; half++)
                qf[mi][half] = *(const short8*)(Qbase
                    + (size_t)(qb + mi * 16 + l16) * 64 + half * 32 + quad * 8);

        float4v acc[2][4] = {};
        float4v accl[2]   = {};

        for (int kt = 0; kt <= qt; kt++) {
            __syncthreads();   // drains staging of current seq; fences prior readers
            // prefetch next stage in the continuous sequence (overlaps compute)
            if (kt < qt)        stage((seq + 1) & 1, kt + 1);
            else if (tph == 0)  stage((seq + 1) & 1, 0);
            const unsigned short* Kc = &Ks[seq & 1][0];
            const unsigned short* Vc = &Vs[seq & 1][0];

            // ---- S = Q . K^T (16 MFMAs) ----
            float4v s_[2][4];
            #pragma unroll
            for (int js = 0; js < 4; js++) {
                int srow = js * 16 + l16, sw = srow & 7;
                short8 kb0 = *(const short8*)((const char*)Kc + srow * 128 + ((quad ^ sw) * 16));
                short8 kb1 = *(const short8*)((const char*)Kc + srow * 128 + (((4 + quad) ^ sw) * 16));
                #pragma unroll
                for (int mi = 0; mi < 2; mi++) {
                    float4v z = {};
                    z = mfma16(qf[mi][0], kb0, z);
                    s_[mi][js] = mfma16(qf[mi][1], kb1, z);
                }
            }

            // ---- causal mask (diagonal tile only) ----
            if (kt == qt) {
                #pragma unroll
                for (int mi = 0; mi < 2; mi++)
                    #pragma unroll
                    for (int js = 0; js < 4; js++) {
                        int coll = js * 16 + l16;
                        #pragma unroll
                        for (int r = 0; r < 4; r++) {
                            int rowl = (wave & 1) * 32 + mi * 16 + quad * 4 + r;
                            if (coll > rowl) s_[mi][js][r] = -1e30f;
                        }
                    }
            }

            // ---- P = exp2(s), packed b64 store (sigma makes 4 cols contiguous) ----
            #pragma unroll
            for (int mi = 0; mi < 2; mi++)
                #pragma unroll
                for (int r = 0; r < 4; r++) {
                    float e0 = __builtin_amdgcn_exp2f(s_[mi][0][r]);
                    float e1 = __builtin_amdgcn_exp2f(s_[mi][1][r]);
                    float e2 = __builtin_amdgcn_exp2f(s_[mi][2][r]);
                    float e3 = __builtin_amdgcn_exp2f(s_[mi][3][r]);
                    unsigned long long d =
                        (unsigned long long)pk2bf(e0, e1) |
                        ((unsigned long long)pk2bf(e2, e3) << 32);
                    int rho = mi * 16 + quad * 4 + r;
                    int ch  = l16 ^ (((quad * 4 + r) & 7) << 1);
                    *(unsigned long long*)(Pw + rho * 128 + ch * 8) = d;
                }

            // ---- P A-frags (b128) + PV (16 MFMAs) + row-sums (4 MFMAs) ----
            short8 pa[2][2];
            #pragma unroll
            for (int mi = 0; mi < 2; mi++)
                #pragma unroll
                for (int half = 0; half < 2; half++) {
                    int chp = (2 * (half * 4 + quad)) ^ ((l16 & 7) << 1);
                    pa[mi][half] = *(const short8*)(Pw + (mi * 16 + l16) * 128 + chp * 8);
                }
            #pragma unroll
            for (int dj = 0; dj < 4; dj++) {
                int vrow = dj * 16 + l16, sw = vrow & 7;
                short8 vb0 = *(const short8*)((const char*)Vc + vrow * 128 + ((quad ^ sw) * 16));
                short8 vb1 = *(const short8*)((const char*)Vc + vrow * 128 + (((4 + quad) ^ sw) * 16));
                #pragma unroll
                for (int mi = 0; mi < 2; mi++) {
                    acc[mi][dj] = mfma16(pa[mi][0], vb0, acc[mi][dj]);
                    acc[mi][dj] = mfma16(pa[mi][1], vb1, acc[mi][dj]);
                }
            }
            #pragma unroll
            for (int mi = 0; mi < 2; mi++) {
                accl[mi] = mfma16(pa[mi][0], ones, accl[mi]);
                accl[mi] = mfma16(pa[mi][1], ones, accl[mi]);
            }
            seq++;
        }

        // ---- epilogue for this q-tile: y[b][t][h*64+d] = acc / l ----
        #pragma unroll
        for (int mi = 0; mi < 2; mi++) {
            float rinv[4];
            #pragma unroll
            for (int r = 0; r < 4; r++) rinv[r] = 1.0f / accl[mi][r];
            #pragma unroll
            for (int dj = 0; dj < 4; dj++)
                #pragma unroll
                for (int r = 0; r < 4; r++) {
                    int tt = qb + mi * 16 + quad * 4 + r;
                    ybase[(size_t)tt * CC + dj * 16 + l16] = f2b(acc[mi][dj][r] * rinv[r]);
                }
        }
    }
}

// ---------------------------------------------------------------------------
extern "C" void kernel_launch(void* const* d_in, const int* in_sizes, int n_in,
                              void* d_out, int out_size, void* d_ws, size_t ws_size,
                              hipStream_t stream) {
    const float* x  = (const float*)d_in[0];
    const float* Wq = (const float*)d_in[1];
    const float* Wk = (const float*)d_in[2];
    const float* Wv = (const float*)d_in[3];
    const float* Wo = (const float*)d_in[4];
    float* out = (float*)d_out;

    char* ws = (char*)d_ws;
    size_t off = 0;
    unsigned short* xb = (unsigned short*)(ws + off); off += (size_t)MROWS * CC * 2;
    unsigned short* Qr = (unsigned short*)(ws + off); off += (size_t)BB * HH  * TT * 64 * 2;
    unsigned short* Kr = (unsigned short*)(ws + off); off += (size_t)BB * KVH * TT * 64 * 2;
    unsigned short* Vt = (unsigned short*)(ws + off); off += (size_t)BB * KVH * TT * 64 * 2;
    unsigned short* y  = (unsigned short*)(ws + off); off += (size_t)MROWS * CC * 2;
    unsigned short* WqkvT = (unsigned short*)(ws + off); off += (size_t)QKVW * CC * 2;
    unsigned short* WoT   = (unsigned short*)(ws + off); off += (size_t)CC * CC * 2;
    float* cosT = (float*)(ws + off); off += (size_t)TT * 32 * 4;
    float* sinT = (float*)(ws + off); off += (size_t)TT * 32 * 4;

    prep_kernel<<<CVT_BLOCKS + 816, 256, 0, stream>>>(x, xb, Wq, Wk, Wv, Wo,
                                                      WqkvT, WoT, cosT, sinT);
    gemm_qkv_kernel<<<(MROWS / 128) * 4, 256, 0, stream>>>(xb, WqkvT, Qr, Kr, Vt, cosT, sinT);
    attn_kernel<<<BB * KVH * 3, 256, 0, stream>>>(Qr, Kr, Vt, y);
    gemm_out_kernel<<<(MROWS / 128) * 2, 256, 0, stream>>>(y, WoT, out);
}

// Round 11
// 157.794 us; speedup vs baseline: 1.0464x; 1.0126x over previous
//
#include <hip/hip_runtime.h>
#include <hip/hip_bf16.h>

// Problem constants
#define BB 128
#define TT 384
#define CC 256
#define HH 4
#define KVH 2
#define QKVW 512
#define MROWS (BB * TT)   // 49152

#define CVT_BLOCKS 6144   // x fp32->bf16: 12.58M elems, 8/thread

typedef __attribute__((ext_vector_type(8))) short short8;
typedef __attribute__((ext_vector_type(4))) float float4v;

__device__ __forceinline__ unsigned short f2b(float f) {
    union { float f; unsigned u; } v; v.f = f;
    unsigned u = v.u;
    unsigned r = (u + 0x7fffu + ((u >> 16) & 1u)) >> 16;
    return (unsigned short)r;
}
__device__ __forceinline__ float4v mfma16(short8 a, short8 b, float4v c) {
    return __builtin_amdgcn_mfma_f32_16x16x32_bf16(a, b, c, 0, 0, 0);
}
// Async global->LDS, 16B per lane. LDS dest = wave-uniform ptr + lane*16.
__device__ __forceinline__ void g2lds16(const void* g, void* l) {
    __builtin_amdgcn_global_load_lds(
        (const __attribute__((address_space(1))) unsigned int*)g,
        (__attribute__((address_space(3))) unsigned int*)l, 16, 0, 0);
}
// Pack high-halves of (a,b) with +0x8000 rounding into one dword [b_hi:a_hi].
__device__ __forceinline__ unsigned pk2bf(float a, float b) {
    union { float f; unsigned u; } x, y; x.f = a; y.f = b;
    return __builtin_amdgcn_perm(y.u + 0x8000u, x.u + 0x8000u, 0x07060302u);
}

// ---------------------------------------------------------------------------
// Prep (fused): [blocks 0..CVT_BLOCKS) convert x fp32->bf16 (8 elems/thread);
// remaining blocks pack W^T bf16 + fp64-accurate RoPE tables.
// ---------------------------------------------------------------------------
__global__ void prep_kernel(const float* __restrict__ x, unsigned short* __restrict__ xb,
                            const float* __restrict__ Wq, const float* __restrict__ Wk,
                            const float* __restrict__ Wv, const float* __restrict__ Wo,
                            unsigned short* __restrict__ WqkvT, unsigned short* __restrict__ WoT,
                            float* __restrict__ cosT, float* __restrict__ sinT) {
    if (blockIdx.x < CVT_BLOCKS) {
        size_t e = ((size_t)blockIdx.x * 256 + threadIdx.x) * 8;
        const float4* p = (const float4*)(x + e);
        float4 v0 = p[0], v1 = p[1];
        short8 w;
        w[0]=(short)f2b(v0.x); w[1]=(short)f2b(v0.y); w[2]=(short)f2b(v0.z); w[3]=(short)f2b(v0.w);
        w[4]=(short)f2b(v1.x); w[5]=(short)f2b(v1.y); w[6]=(short)f2b(v1.z); w[7]=(short)f2b(v1.w);
        *(short8*)(xb + e) = w;
        return;
    }
    int idx = (blockIdx.x - CVT_BLOCKS) * 256 + threadIdx.x;
    const int N1 = QKVW * CC;          // 131072
    const int N2 = N1 + CC * CC;       // +65536
    const int N3 = N2 + TT * 32;       // +12288
    if (idx < N1) {
        int n = idx >> 8, k = idx & 255;
        float w;
        if (n < 256)      w = Wq[k * 256 + n];
        else if (n < 384) w = Wk[k * 128 + (n - 256)];
        else              w = Wv[k * 128 + (n - 384)];
        WqkvT[n * 256 + k] = f2b(w);
    } else if (idx < N2) {
        int i = idx - N1; int n = i >> 8, k = i & 255;
        WoT[n * 256 + k] = f2b(Wo[k * 256 + n]);
    } else if (idx < N3) {
        int i = idx - N2;
        int t = i >> 5, f = i & 31;
        double invf = exp2(-(double)f / 32.0 * 13.287712379549449);  // 10000^(-f/32)
        double ang = (double)t * invf;
        cosT[t * 32 + f] = (float)cos(ang);
        sinT[t * 32 + f] = (float)sin(ang);
    }
}

// ---------------------------------------------------------------------------
// GEMM1 (R11): qkv = xb @ [Wq|Wk|Wv]. R11 change: BK 32->64 — halves the
// per-block stall events (4 K-steps x 2 barriers instead of 8 x 2) and
// doubles compute cover per stall (32 MFMAs/step). Measured signature this
// targets (R5/R6): MfmaUtil 10%, VALUBusy 22%, HBM 21% = per-step
// stall-bound. The 64-wide chunk is stored as TWO [128][32] sub-tiles
// (row-major [128][64] would be 16-way bank-conflicted); fragment reads
// per sub-tile identical to the verified BK=32 path. Accumulation order
// unchanged (K ascending by 32) -> bit-identical numerics.
// Same 2-barrier __syncthreads skeleton (R8/R9: raw-barrier edits fail).
// ---------------------------------------------------------------------------
__global__ __launch_bounds__(256) void gemm_qkv_kernel(
    const unsigned short* __restrict__ A, const unsigned short* __restrict__ BT,
    unsigned short* __restrict__ Qr, unsigned short* __restrict__ Kr,
    unsigned short* __restrict__ Vt,
    const float* __restrict__ cosT, const float* __restrict__ sinT)
{
    __shared__ __align__(16) unsigned short As[2][128 * 32];   // kk sub-tiles
    __shared__ __align__(16) unsigned short Bs[2][128 * 32];
    const int tid  = threadIdx.x;
    const int lane = tid & 63;
    const int quad = lane >> 4, l16 = lane & 15;
    const int wave = tid >> 6;
    const int mt = ((blockIdx.x >> 5) << 3) | (blockIdx.x & 7);
    const int nt = (blockIdx.x >> 3) & 3;
    const int mbase = mt * 128, nbase = nt * 128;
    const int wmb = (wave >> 1) * 64, wnb = (wave & 1) * 64;

    float4v acc[4][4] = {};
    const int r0 = tid >> 2, kc = (tid & 3) * 8;
    const int ldsW = (tid & ~63) * 16;
    const unsigned short* gA0 = A  + (size_t)(mbase + r0) * CC + kc;
    const unsigned short* gB0 = BT + (size_t)(nbase + r0) * CC + kc;

    for (int kt = 0; kt < CC; kt += 64) {
        __syncthreads();
        #pragma unroll
        for (int kk = 0; kk < 2; kk++) {
            g2lds16(gA0 + kt + kk * 32,                  (char*)&As[kk][0] + ldsW);
            g2lds16(gA0 + kt + kk * 32 + (size_t)64*CC,  (char*)&As[kk][0] + 4096 + ldsW);
            g2lds16(gB0 + kt + kk * 32,                  (char*)&Bs[kk][0] + ldsW);
            g2lds16(gB0 + kt + kk * 32 + (size_t)64*CC,  (char*)&Bs[kk][0] + 4096 + ldsW);
        }
        __syncthreads();

        #pragma unroll
        for (int kk = 0; kk < 2; kk++) {
            short8 af[4], bf_[4];
            #pragma unroll
            for (int i = 0; i < 4; i++)
                af[i] = *(const short8*)&As[kk][(wmb + i * 16 + l16) * 32 + quad * 8];
            #pragma unroll
            for (int i = 0; i < 4; i++)
                bf_[i] = *(const short8*)&Bs[kk][(wnb + i * 16 + l16) * 32 + quad * 8];
            #pragma unroll
            for (int i = 0; i < 4; i++)
                #pragma unroll
                for (int j = 0; j < 4; j++)
                    acc[i][j] = mfma16(af[i], bf_[j], acc[i][j]);
        }
    }

    const int gn0 = nbase + wnb;
    const int gm0 = mbase + wmb;
    if (gn0 < 384) {
        const bool isq = (gn0 < 256);
        const int  hh  = isq ? (gn0 >> 6) : ((gn0 - 256) >> 6);
        const float qs = isq ? 0.18033688011112042f : 1.0f;   // 0.125 * log2(e)
        #pragma unroll
        for (int i = 0; i < 4; i++) {
            #pragma unroll
            for (int r = 0; r < 4; r++) {
                int gm = gm0 + i * 16 + quad * 4 + r;
                int b = gm / TT, t = gm - b * TT;
                unsigned short* dst = isq
                    ? (Qr + (((size_t)b * HH  + hh) * TT + t) * 64)
                    : (Kr + (((size_t)b * KVH + hh) * TT + t) * 64);
                #pragma unroll
                for (int j = 0; j < 2; j++) {
                    int f = j * 16 + l16;
                    float cs = cosT[t * 32 + f], sn = sinT[t * 32 + f];
                    float a  = acc[i][j][r],     c2 = acc[i][j + 2][r];
                    dst[f]      = f2b((a * cs - c2 * sn) * qs);
                    dst[f + 32] = f2b((c2 * cs + a * sn) * qs);
                }
            }
        }
    } else {
        const int g = (gn0 - 384) >> 6;
        #pragma unroll
        for (int i = 0; i < 4; i++) {
            #pragma unroll
            for (int r = 0; r < 4; r++) {
                int gm = gm0 + i * 16 + quad * 4 + r;
                int b = gm / TT, s = gm - b * TT;
                int s6 = s & 63;
                int sig = (s6 & 15) * 4 + (s6 >> 4);   // key permutation
                unsigned short* dst = Vt + (((size_t)b * KVH + g) * 6 + (s >> 6)) * 4096 + sig;
                #pragma unroll
                for (int j = 0; j < 4; j++)
                    dst[(j * 16 + l16) * 64] = f2b(acc[i][j][r]);
            }
        }
    }
}

// ---------------------------------------------------------------------------
// GEMM2 (R11): out = y @ Wo, out fp32. Same BK=64 parameter change.
// ---------------------------------------------------------------------------
__global__ __launch_bounds__(256) void gemm_out_kernel(
    const unsigned short* __restrict__ A, const unsigned short* __restrict__ BT,
    float* __restrict__ C)
{
    __shared__ __align__(16) unsigned short As[2][128 * 32];
    __shared__ __align__(16) unsigned short Bs[2][128 * 32];
    const int tid  = threadIdx.x;
    const int lane = tid & 63;
    const int quad = lane >> 4, l16 = lane & 15;
    const int wave = tid >> 6;
    const int mt = ((blockIdx.x >> 4) << 3) | (blockIdx.x & 7);
    const int nt = (blockIdx.x >> 3) & 1;
    const int mbase = mt * 128, nbase = nt * 128;
    const int wmb = (wave >> 1) * 64, wnb = (wave & 1) * 64;

    float4v acc[4][4] = {};
    const int r0 = tid >> 2, kc = (tid & 3) * 8;
    const int ldsW = (tid & ~63) * 16;
    const unsigned short* gA0 = A  + (size_t)(mbase + r0) * CC + kc;
    const unsigned short* gB0 = BT + (size_t)(nbase + r0) * CC + kc;

    for (int kt = 0; kt < CC; kt += 64) {
        __syncthreads();
        #pragma unroll
        for (int kk = 0; kk < 2; kk++) {
            g2lds16(gA0 + kt + kk * 32,                  (char*)&As[kk][0] + ldsW);
            g2lds16(gA0 + kt + kk * 32 + (size_t)64*CC,  (char*)&As[kk][0] + 4096 + ldsW);
            g2lds16(gB0 + kt + kk * 32,                  (char*)&Bs[kk][0] + ldsW);
            g2lds16(gB0 + kt + kk * 32 + (size_t)64*CC,  (char*)&Bs[kk][0] + 4096 + ldsW);
        }
        __syncthreads();

        #pragma unroll
        for (int kk = 0; kk < 2; kk++) {
            short8 af[4], bf_[4];
            #pragma unroll
            for (int i = 0; i < 4; i++)
                af[i] = *(const short8*)&As[kk][(wmb + i * 16 + l16) * 32 + quad * 8];
            #pragma unroll
            for (int i = 0; i < 4; i++)
                bf_[i] = *(const short8*)&Bs[kk][(wnb + i * 16 + l16) * 32 + quad * 8];
            #pragma unroll
            for (int i = 0; i < 4; i++)
                #pragma unroll
                for (int j = 0; j < 4; j++)
                    acc[i][j] = mfma16(af[i], bf_[j], acc[i][j]);
        }
    }
    #pragma unroll
    for (int i = 0; i < 4; i++)
        #pragma unroll
        for (int j = 0; j < 4; j++)
            #pragma unroll
            for (int r = 0; r < 4; r++)
                C[(size_t)(mbase + wmb + i * 16 + quad * 4 + r) * CC + nbase + wnb + j * 16 + l16]
                    = acc[i][j][r];
}

// ---------------------------------------------------------------------------
// Attention v4 (unchanged, verified): block = (b, g, p), 7 stages/block,
// K/V double-buffered, continuous stage stream, sigma-permuted P via
// ds_write_b64, fixed-max softmax, row-sums via ones-MFMA. No shuffles.
// ---------------------------------------------------------------------------
__global__ __launch_bounds__(256, 3) void attn_kernel(
    const unsigned short* __restrict__ Qr, const unsigned short* __restrict__ Kr,
    const unsigned short* __restrict__ Vt, unsigned short* __restrict__ y)
{
    __shared__ __align__(16) unsigned short Ks[2][64 * 64];  // 2 x 8 KB, XOR-swizzled [s][d]
    __shared__ __align__(16) unsigned short Vs[2][64 * 64];  // 2 x 8 KB, XOR-swizzled [d][sigma]
    __shared__ __align__(16) unsigned short Ps[4][32 * 64];  // per-wave [q][sigma], row-XOR

    const int tid  = threadIdx.x;
    const int lane = tid & 63;
    const int wave = tid >> 6;
    const int quad = lane >> 4, l16 = lane & 15;

    // decode with XCD co-location: all 3 p-blocks of (b,g) share bid&7
    const int xc  = blockIdx.x & 7;
    const int jj  = blockIdx.x >> 3;        // 0..95
    const int p   = jj % 3;
    const int bg  = (jj / 3) * 8 + xc;      // 0..255
    const int g   = bg & 1, b = bg >> 1;
    const int h   = g * 2 + (wave >> 1);

    const unsigned short* Kbase = Kr + ((size_t)b * KVH + g) * TT * 64;
    const unsigned short* Vbase = Vt + ((size_t)b * KVH + g) * 6 * 4096;
    const unsigned short* Qbase = Qr + ((size_t)b * HH + h) * TT * 64;
    unsigned short* ybase = y + (size_t)b * TT * CC + h * 64;
    char* Pw = (char*)&Ps[wave][0];
    const int ldsWave = (tid & ~63) * 16;
    int gc0, gc1;
    { int L0 = tid;       gc0 = ((L0 & ~7) | ((L0 & 7) ^ ((L0 >> 3) & 7))) * 8;
      int L1 = 256 + tid; gc1 = ((L1 & ~7) | ((L1 & 7) ^ ((L1 >> 3) & 7))) * 8; }

    auto stage = [&](int bi, int kt) {
        const unsigned short* kB = Kbase + (size_t)kt * 4096;
        const unsigned short* vB = Vbase + (size_t)kt * 4096;
        g2lds16(kB + gc0, (char*)&Ks[bi][0] + ldsWave);
        g2lds16(kB + gc1, (char*)&Ks[bi][0] + 4096 + ldsWave);
        g2lds16(vB + gc0, (char*)&Vs[bi][0] + ldsWave);
        g2lds16(vB + gc1, (char*)&Vs[bi][0] + 4096 + ldsWave);
    };

    short8 ones;
    #pragma unroll
    for (int j = 0; j < 8; j++) ones[j] = (short)0x3F80;   // bf16 1.0

    int seq = 0;          // global stage counter -> buffer parity
    stage(0, 0);

    for (int tph = 0; tph < 2; tph++) {
        const int qt = tph ? (5 - p) : p;
        const int qb = qt * 64 + (wave & 1) * 32;   // this wave's 32 q-rows

        // Q fragments (A-layout): m = l16, k = half*32 + quad*8
        short8 qf[2][2];
        #pragma unroll
        for (int mi = 0; mi < 2; mi++)
            #pragma unroll
            for (int half = 0; half < 2; half++)
                qf[mi][half] = *(const short8*)(Qbase
                    + (size_t)(qb + mi * 16 + l16) * 64 + half * 32 + quad * 8);

        float4v acc[2][4] = {};
        float4v accl[2]   = {};

        for (int kt = 0; kt <= qt; kt++) {
            __syncthreads();   // drains staging of current seq; fences prior readers
            // prefetch next stage in the continuous sequence (overlaps compute)
            if (kt < qt)        stage((seq + 1) & 1, kt + 1);
            else if (tph == 0)  stage((seq + 1) & 1, 0);
            const unsigned short* Kc = &Ks[seq & 1][0];
            const unsigned short* Vc = &Vs[seq & 1][0];

            // ---- S = Q . K^T (16 MFMAs) ----
            float4v s_[2][4];
            #pragma unroll
            for (int js = 0; js < 4; js++) {
                int srow = js * 16 + l16, sw = srow & 7;
                short8 kb0 = *(const short8*)((const char*)Kc + srow * 128 + ((quad ^ sw) * 16));
                short8 kb1 = *(const short8*)((const char*)Kc + srow * 128 + (((4 + quad) ^ sw) * 16));
                #pragma unroll
                for (int mi = 0; mi < 2; mi++) {
                    float4v z = {};
                    z = mfma16(qf[mi][0], kb0, z);
                    s_[mi][js] = mfma16(qf[mi][1], kb1, z);
                }
            }

            // ---- causal mask (diagonal tile only) ----
            if (kt == qt) {
                #pragma unroll
                for (int mi = 0; mi < 2; mi++)
                    #pragma unroll
                    for (int js = 0; js < 4; js++) {
                        int coll = js * 16 + l16;
                        #pragma unroll
                        for (int r = 0; r < 4; r++) {
                            int rowl = (wave & 1) * 32 + mi * 16 + quad * 4 + r;
                            if (coll > rowl) s_[mi][js][r] = -1e30f;
                        }
                    }
            }

            // ---- P = exp2(s), packed b64 store (sigma makes 4 cols contiguous) ----
            #pragma unroll
            for (int mi = 0; mi < 2; mi++)
                #pragma unroll
                for (int r = 0; r < 4; r++) {
                    float e0 = __builtin_amdgcn_exp2f(s_[mi][0][r]);
                    float e1 = __builtin_amdgcn_exp2f(s_[mi][1][r]);
                    float e2 = __builtin_amdgcn_exp2f(s_[mi][2][r]);
                    float e3 = __builtin_amdgcn_exp2f(s_[mi][3][r]);
                    unsigned long long d =
                        (unsigned long long)pk2bf(e0, e1) |
                        ((unsigned long long)pk2bf(e2, e3) << 32);
                    int rho = mi * 16 + quad * 4 + r;
                    int ch  = l16 ^ (((quad * 4 + r) & 7) << 1);
                    *(unsigned long long*)(Pw + rho * 128 + ch * 8) = d;
                }

            // ---- P A-frags (b128) + PV (16 MFMAs) + row-sums (4 MFMAs) ----
            short8 pa[2][2];
            #pragma unroll
            for (int mi = 0; mi < 2; mi++)
                #pragma unroll
                for (int half = 0; half < 2; half++) {
                    int chp = (2 * (half * 4 + quad)) ^ ((l16 & 7) << 1);
                    pa[mi][half] = *(const short8*)(Pw + (mi * 16 + l16) * 128 + chp * 8);
                }
            #pragma unroll
            for (int dj = 0; dj < 4; dj++) {
                int vrow = dj * 16 + l16, sw = vrow & 7;
                short8 vb0 = *(const short8*)((const char*)Vc + vrow * 128 + ((quad ^ sw) * 16));
                short8 vb1 = *(const short8*)((const char*)Vc + vrow * 128 + (((4 + quad) ^ sw) * 16));
                #pragma unroll
                for (int mi = 0; mi < 2; mi++) {
                    acc[mi][dj] = mfma16(pa[mi][0], vb0, acc[mi][dj]);
                    acc[mi][dj] = mfma16(pa[mi][1], vb1, acc[mi][dj]);
                }
            }
            #pragma unroll
            for (int mi = 0; mi < 2; mi++) {
                accl[mi] = mfma16(pa[mi][0], ones, accl[mi]);
                accl[mi] = mfma16(pa[mi][1], ones, accl[mi]);
            }
            seq++;
        }

        // ---- epilogue for this q-tile: y[b][t][h*64+d] = acc / l ----
        #pragma unroll
        for (int mi = 0; mi < 2; mi++) {
            float rinv[4];
            #pragma unroll
            for (int r = 0; r < 4; r++) rinv[r] = 1.0f / accl[mi][r];
            #pragma unroll
            for (int dj = 0; dj < 4; dj++)
                #pragma unroll
                for (int r = 0; r < 4; r++) {
                    int tt = qb + mi * 16 + quad * 4 + r;
                    ybase[(size_t)tt * CC + dj * 16 + l16] = f2b(acc[mi][dj][r] * rinv[r]);
                }
        }
    }
}

// ---------------------------------------------------------------------------
extern "C" void kernel_launch(void* const* d_in, const int* in_sizes, int n_in,
                              void* d_out, int out_size, void* d_ws, size_t ws_size,
                              hipStream_t stream) {
    const float* x  = (const float*)d_in[0];
    const float* Wq = (const float*)d_in[1];
    const float* Wk = (const float*)d_in[2];
    const float* Wv = (const float*)d_in[3];
    const float* Wo = (const float*)d_in[4];
    float* out = (float*)d_out;

    char* ws = (char*)d_ws;
    size_t off = 0;
    unsigned short* xb = (unsigned short*)(ws + off); off += (size_t)MROWS * CC * 2;
    unsigned short* Qr = (unsigned short*)(ws + off); off += (size_t)BB * HH  * TT * 64 * 2;
    unsigned short* Kr = (unsigned short*)(ws + off); off += (size_t)BB * KVH * TT * 64 * 2;
    unsigned short* Vt = (unsigned short*)(ws + off); off += (size_t)BB * KVH * TT * 64 * 2;
    unsigned short* y  = (unsigned short*)(ws + off); off += (size_t)MROWS * CC * 2;
    unsigned short* WqkvT = (unsigned short*)(ws + off); off += (size_t)QKVW * CC * 2;
    unsigned short* WoT   = (unsigned short*)(ws + off); off += (size_t)CC * CC * 2;
    float* cosT = (float*)(ws + off); off += (size_t)TT * 32 * 4;
    float* sinT = (float*)(ws + off); off += (size_t)TT * 32 * 4;

    prep_kernel<<<CVT_BLOCKS + 816, 256, 0, stream>>>(x, xb, Wq, Wk, Wv, Wo,
                                                      WqkvT, WoT, cosT, sinT);
    gemm_qkv_kernel<<<(MROWS / 128) * 4, 256, 0, stream>>>(xb, WqkvT, Qr, Kr, Vt, cosT, sinT);
    attn_kernel<<<BB * KVH * 3, 256, 0, stream>>>(Qr, Kr, Vt, y);
    gemm_out_kernel<<<(MROWS / 128) * 2, 256, 0, stream>>>(y, WoT, out);
}